// Round 1
// baseline (1271.510 us; speedup 1.0000x reference)
//
#include <hip/hip_runtime.h>
#include <math.h>

// EGNN: B=64 graphs x N=64 nodes, D=3, IN_NF=8, H=128, L=4 layers.
// Key factorization: e_in @ ew1 = P[row] + Q[col] + radial*w256 + ea*w257
// where P = h@ew1[0:128]+eb1, Q = h@ew1[128:256] are per-NODE GEMMs.
// Per-edge work left: t1=silu(.), m=silu(t1@ew2+eb2), c1=silu(m@cw1+cb1),
// phi=c1@cw2, trans, and row-segment sums (64 consecutive edges per row
// -> one block per row node, no atomics).

#define NB 64
#define NN 64
#define DD 3
#define INNF 8
#define HH 128
#define LL 4
#define BNODES (NB * NN)  // 4096
#define STRA 68           // padded stride for K-major LDS tiles

__device__ __forceinline__ float silu_f(float v) {
    return v / (1.0f + __expf(-v));
}

// ---------------- prep: x, x0, h = (feat*nm)@emb_w + emb_b ----------------
__global__ void prep_kernel(const float* __restrict__ xh, const float* __restrict__ nm,
                            const float* __restrict__ emb_w, const float* __restrict__ emb_b,
                            float* __restrict__ x, float* __restrict__ x0, float* __restrict__ h) {
    const int v = blockIdx.x;
    const int t = threadIdx.x;  // 128
    const float m = nm[v];
    __shared__ float f[INNF];
    if (t < INNF) f[t] = xh[v * (DD + INNF) + DD + t] * m;
    if (t < DD) {
        float c = xh[v * (DD + INNF) + t] * m;
        x[v * DD + t] = c;
        x0[v * DD + t] = c;
    }
    __syncthreads();
    float acc = emb_b[t];
#pragma unroll
    for (int k = 0; k < INNF; ++k) acc = fmaf(f[k], emb_w[k * HH + t], acc);
    h[v * HH + t] = acc;
}

// ---------------- per-layer: P = h@Wr + eb1, Q = h@Wc ----------------
__global__ __launch_bounds__(256) void pq_kernel(const float* __restrict__ h,
                                                 const float* __restrict__ ew1l,
                                                 const float* __restrict__ eb1l,
                                                 float* __restrict__ P, float* __restrict__ Q) {
    const int v = blockIdx.x;
    const int t = threadIdx.x;  // 256
    __shared__ float shh[HH];
    if (t < HH) shh[t] = h[v * HH + t];
    __syncthreads();
    const int c = t & (HH - 1);
    const int which = t >> 7;  // 0: P, 1: Q
    const float* W = ew1l + which * HH * HH;
    float acc = which ? 0.0f : eb1l[c];
#pragma unroll 8
    for (int k = 0; k < HH; ++k) acc = fmaf(shh[k], W[k * HH + c], acc);
    if (which) Q[v * HH + c] = acc;
    else P[v * HH + c] = acc;
}

// ---------------- per-layer edge kernel: one block per row-node ----------------
__global__ __launch_bounds__(256) void edge_kernel(
    const float* __restrict__ P, const float* __restrict__ Q,
    const float* __restrict__ x, const float* __restrict__ x0,
    const float* __restrict__ em,
    const float* __restrict__ ew1l,   // [258][128] (rows 256,257 used)
    const float* __restrict__ ew2l,   // [128][128]
    const float* __restrict__ eb2l,   // [128]
    const float* __restrict__ cw1l,   // [128][128]
    const float* __restrict__ cb1l,   // [128]
    const float* __restrict__ cw2l,   // [128]
    float* __restrict__ x_out, float* __restrict__ agg) {

    const int r = blockIdx.x;
    const int i = r & (NN - 1);
    const int g0 = (r >> 6) << 6;  // first node of this graph
    const int t = threadIdx.x;     // 256

    __shared__ float shA[HH * STRA];  // K-major: t1^T then m^T (34816 B)
    __shared__ float shB[16 * HH];    // weight chunk staging (8192 B)
    __shared__ float shP[HH], shw256[HH], shw257[HH];
    __shared__ float shx[NN * 3], shx0g[NN * 3];
    __shared__ float shrad[NN], shea[NN], shem[NN], shcdn[NN * 3], shphi[NN];
    __shared__ float shagg[8 * HH];   // per-et partial agg (4096 B)

    if (t < NN * 3) { shx[t] = x[g0 * 3 + t]; shx0g[t] = x0[g0 * 3 + t]; }
    if (t < HH) {
        shP[t] = P[r * HH + t];
        shw256[t] = ew1l[256 * HH + t];
        shw257[t] = ew1l[257 * HH + t];
    }
    __syncthreads();
    if (t < NN) {
        const int j = t;
        float dx = shx[i * 3 + 0] - shx[j * 3 + 0];
        float dy = shx[i * 3 + 1] - shx[j * 3 + 1];
        float dz = shx[i * 3 + 2] - shx[j * 3 + 2];
        float rad = dx * dx + dy * dy + dz * dz;
        shrad[j] = rad;
        float inv = 1.0f / (sqrtf(rad + 1e-8f) + 1.0f);
        shcdn[j * 3 + 0] = dx * inv;
        shcdn[j * 3 + 1] = dy * inv;
        shcdn[j * 3 + 2] = dz * inv;
        float ex = shx0g[i * 3 + 0] - shx0g[j * 3 + 0];
        float ey = shx0g[i * 3 + 1] - shx0g[j * 3 + 1];
        float ez = shx0g[i * 3 + 2] - shx0g[j * 3 + 2];
        shea[j] = ex * ex + ey * ey + ez * ez;
        shem[j] = em[r * NN + j];
    }
    __syncthreads();

    // build t1^T: shA[k*STRA+j] = silu(P[k] + Q[g0+j][k] + rad_j*w256[k] + ea_j*w257[k])
#pragma unroll
    for (int pass = 0; pass < 8; ++pass) {
        const int idx = t + pass * 256;
        const int j = idx & 63, kg = idx >> 6;
        float4 q4 = *(const float4*)(Q + (size_t)(g0 + j) * HH + kg * 4);
        const float rad = shrad[j], ea = shea[j];
        float qv[4] = {q4.x, q4.y, q4.z, q4.w};
#pragma unroll
        for (int u = 0; u < 4; ++u) {
            const int k = kg * 4 + u;
            float v = shP[k] + qv[u] + rad * shw256[k] + ea * shw257[k];
            shA[k * STRA + j] = silu_f(v);
        }
    }

    const int ct = t & 31, et = t >> 5;  // 4 cols x 8 edges per thread
    float acc[8][4];
#pragma unroll
    for (int jj = 0; jj < 8; ++jj)
#pragma unroll
        for (int cc = 0; cc < 4; ++cc) acc[jj][cc] = 0.0f;

    // GEMM2: m = t1 @ ew2 (K staged in 16-row chunks through shB)
    for (int kc = 0; kc < 8; ++kc) {
        __syncthreads();
#pragma unroll
        for (int u = 0; u < 2; ++u) {
            const int fid = t * 2 + u;
            const int kk = fid >> 5, c4 = fid & 31;
            *(float4*)(shB + kk * HH + c4 * 4) =
                *(const float4*)(ew2l + (size_t)(kc * 16 + kk) * HH + c4 * 4);
        }
        __syncthreads();
#pragma unroll
        for (int kk = 0; kk < 16; ++kk) {
            const int k = kc * 16 + kk;
            float4 a0 = *(const float4*)(shA + k * STRA + et * 8);
            float4 a1 = *(const float4*)(shA + k * STRA + et * 8 + 4);
            float4 b4 = *(const float4*)(shB + kk * HH + ct * 4);
            float av[8] = {a0.x, a0.y, a0.z, a0.w, a1.x, a1.y, a1.z, a1.w};
            float bv[4] = {b4.x, b4.y, b4.z, b4.w};
#pragma unroll
            for (int jj = 0; jj < 8; ++jj)
#pragma unroll
                for (int cc = 0; cc < 4; ++cc)
                    acc[jj][cc] = fmaf(av[jj], bv[cc], acc[jj][cc]);
        }
    }
    __syncthreads();  // all GEMM2 reads of shA done

    // m = silu(acc + eb2) * em -> write m^T into shA, partial agg
    {
        float aggp[4] = {0, 0, 0, 0};
#pragma unroll
        for (int jj = 0; jj < 8; ++jj) {
            const int j = et * 8 + jj;
            const float emj = shem[j];
#pragma unroll
            for (int cc = 0; cc < 4; ++cc) {
                const int c = ct * 4 + cc;
                float v = silu_f(acc[jj][cc] + eb2l[c]) * emj;
                shA[c * STRA + j] = v;
                aggp[cc] += v;
            }
        }
#pragma unroll
        for (int cc = 0; cc < 4; ++cc) shagg[et * HH + ct * 4 + cc] = aggp[cc];
    }

    // GEMM3: c1 = m @ cw1
#pragma unroll
    for (int jj = 0; jj < 8; ++jj)
#pragma unroll
        for (int cc = 0; cc < 4; ++cc) acc[jj][cc] = 0.0f;
    for (int kc = 0; kc < 8; ++kc) {
        __syncthreads();  // (kc=0 also fences the m^T writes above)
#pragma unroll
        for (int u = 0; u < 2; ++u) {
            const int fid = t * 2 + u;
            const int kk = fid >> 5, c4 = fid & 31;
            *(float4*)(shB + kk * HH + c4 * 4) =
                *(const float4*)(cw1l + (size_t)(kc * 16 + kk) * HH + c4 * 4);
        }
        __syncthreads();
#pragma unroll
        for (int kk = 0; kk < 16; ++kk) {
            const int k = kc * 16 + kk;
            float4 a0 = *(const float4*)(shA + k * STRA + et * 8);
            float4 a1 = *(const float4*)(shA + k * STRA + et * 8 + 4);
            float4 b4 = *(const float4*)(shB + kk * HH + ct * 4);
            float av[8] = {a0.x, a0.y, a0.z, a0.w, a1.x, a1.y, a1.z, a1.w};
            float bv[4] = {b4.x, b4.y, b4.z, b4.w};
#pragma unroll
            for (int jj = 0; jj < 8; ++jj)
#pragma unroll
                for (int cc = 0; cc < 4; ++cc)
                    acc[jj][cc] = fmaf(av[jj], bv[cc], acc[jj][cc]);
        }
    }

    // phi[j] = sum_c silu(c1 + cb1)[j][c] * cw2[c]; reduce across ct (32 lanes)
    {
        float pp[8];
#pragma unroll
        for (int jj = 0; jj < 8; ++jj) pp[jj] = 0.0f;
#pragma unroll
        for (int jj = 0; jj < 8; ++jj) {
#pragma unroll
            for (int cc = 0; cc < 4; ++cc) {
                const int c = ct * 4 + cc;
                float v = silu_f(acc[jj][cc] + cb1l[c]);
                pp[jj] = fmaf(v, cw2l[c], pp[jj]);
            }
        }
#pragma unroll
        for (int off = 16; off >= 1; off >>= 1) {
#pragma unroll
            for (int jj = 0; jj < 8; ++jj) pp[jj] += __shfl_xor(pp[jj], off);
        }
        if (ct == 0) {
#pragma unroll
            for (int jj = 0; jj < 8; ++jj) shphi[et * 8 + jj] = pp[jj];
        }
    }
    __syncthreads();

    // x_out[r] = x[r] + sum_j cdn[j]*phi[j]*em[j]  (3 waves, one per coord)
    if (t < 192) {
        const int q = t >> 6, j = t & 63;
        float v = shcdn[j * 3 + q] * shphi[j] * shem[j];
#pragma unroll
        for (int off = 32; off >= 1; off >>= 1) v += __shfl_xor(v, off);
        if (j == 0) x_out[r * 3 + q] = shx[i * 3 + q] + v;
    }
    // agg[r][c] = sum over 8 et-partials
    if (t < HH) {
        float s = 0.0f;
#pragma unroll
        for (int e8 = 0; e8 < 8; ++e8) s += shagg[e8 * HH + t];
        agg[r * HH + t] = s;
    }
}

// ---------------- per-layer node update (in place) ----------------
__global__ void node_kernel(float* __restrict__ h, const float* __restrict__ agg,
                            const float* __restrict__ nm,
                            const float* __restrict__ nw1l, const float* __restrict__ nb1l,
                            const float* __restrict__ nw2l, const float* __restrict__ nb2l) {
    const int v = blockIdx.x;
    const int t = threadIdx.x;  // 128
    __shared__ float shh[HH], sha[HH], sht[HH];
    shh[t] = h[v * HH + t];
    sha[t] = agg[v * HH + t];
    __syncthreads();
    float acc = nb1l[t];
#pragma unroll 8
    for (int k = 0; k < HH; ++k) acc = fmaf(shh[k], nw1l[k * HH + t], acc);
#pragma unroll 8
    for (int k = 0; k < HH; ++k) acc = fmaf(sha[k], nw1l[(HH + k) * HH + t], acc);
    sht[t] = silu_f(acc);
    __syncthreads();
    float d = nb2l[t];
#pragma unroll 8
    for (int k = 0; k < HH; ++k) d = fmaf(sht[k], nw2l[k * HH + t], d);
    h[v * HH + t] = (shh[t] + d) * nm[v];
}

// ---------------- output: per-graph mean of (h@out_w + out_b)*nm ----------------
__global__ void out_kernel(const float* __restrict__ h, const float* __restrict__ nm,
                           const float* __restrict__ ow, const float* __restrict__ ob,
                           float* __restrict__ out) {
    const int b = blockIdx.x;
    const int n = threadIdx.x;  // 64
    const int v = b * NN + n;
    float acc = 0.0f;
#pragma unroll 8
    for (int c = 0; c < HH; ++c) acc = fmaf(h[v * HH + c], ow[c], acc);
    acc = (acc + ob[0]) * nm[v];
#pragma unroll
    for (int off = 32; off >= 1; off >>= 1) acc += __shfl_xor(acc, off);
    if (n == 0) out[b] = acc * (1.0f / (float)NN);
}

extern "C" void kernel_launch(void* const* d_in, const int* in_sizes, int n_in,
                              void* d_out, int out_size, void* d_ws, size_t ws_size,
                              hipStream_t stream) {
    const float* xh    = (const float*)d_in[0];
    const float* nmask = (const float*)d_in[1];
    const float* emask = (const float*)d_in[2];
    const float* emb_w = (const float*)d_in[3];
    const float* emb_b = (const float*)d_in[4];
    const float* out_w = (const float*)d_in[5];
    const float* out_b = (const float*)d_in[6];
    const float* ew1   = (const float*)d_in[7];
    const float* eb1   = (const float*)d_in[8];
    const float* ew2   = (const float*)d_in[9];
    const float* eb2   = (const float*)d_in[10];
    const float* nw1   = (const float*)d_in[11];
    const float* nb1   = (const float*)d_in[12];
    const float* nw2   = (const float*)d_in[13];
    const float* nb2   = (const float*)d_in[14];
    const float* cw1   = (const float*)d_in[15];
    const float* cb1   = (const float*)d_in[16];
    const float* cw2   = (const float*)d_in[17];

    float* ws  = (float*)d_ws;
    float* xA  = ws;                    // [4096*3]
    float* xB  = xA + BNODES * 3;       // [4096*3]
    float* x0  = xB + BNODES * 3;       // [4096*3]
    float* h   = x0 + BNODES * 3;       // [4096*128]
    float* Pb  = h + BNODES * HH;       // [4096*128]
    float* Qb  = Pb + BNODES * HH;      // [4096*128]
    float* agg = Qb + BNODES * HH;      // [4096*128]

    prep_kernel<<<BNODES, HH, 0, stream>>>(xh, nmask, emb_w, emb_b, xA, x0, h);

    float* xc = xA;
    float* xn = xB;
    for (int l = 0; l < LL; ++l) {
        const float* ew1l = ew1 + (size_t)l * 258 * HH;
        pq_kernel<<<BNODES, 256, 0, stream>>>(h, ew1l, eb1 + l * HH, Pb, Qb);
        edge_kernel<<<BNODES, 256, 0, stream>>>(Pb, Qb, xc, x0, emask, ew1l,
                                                ew2 + (size_t)l * HH * HH, eb2 + l * HH,
                                                cw1 + (size_t)l * HH * HH, cb1 + l * HH,
                                                cw2 + (size_t)l * HH, xn, agg);
        node_kernel<<<BNODES, HH, 0, stream>>>(h, agg, nmask,
                                               nw1 + (size_t)l * 2 * HH * HH, nb1 + l * HH,
                                               nw2 + (size_t)l * HH * HH, nb2 + l * HH);
        float* tmp = xc; xc = xn; xn = tmp;
    }

    out_kernel<<<NB, NN, 0, stream>>>(h, nmask, out_w, out_b, (float*)d_out);
}

// Round 3
// 703.779 us; speedup vs baseline: 1.8067x; 1.8067x over previous
//
#include <hip/hip_runtime.h>
#include <math.h>

// EGNN: B=64 graphs x N=64 nodes, D=3, IN_NF=8, H=128, L=4 layers.
// e_in @ ew1 = P[row] + Q[col] + radial*w256 + ea*w257 (per-node GEMMs).
// Edge kernel: per-edge GEMM2/GEMM3 on bf16 MFMA (fp32 accumulate),
// t1/m staged in XOR-swizzled LDS, wave-private rows (no inner barriers).

#define NB 64
#define NN 64
#define DD 3
#define INNF 8
#define HH 128
#define LL 4
#define BNODES (NB * NN)  // 4096

typedef __attribute__((ext_vector_type(8))) short bf16x8;
typedef __attribute__((ext_vector_type(4))) float f32x4;

__device__ __forceinline__ float silu_f(float v) {
    float e = __expf(-v);
    return v * __builtin_amdgcn_rcpf(1.0f + e);
}

__device__ __forceinline__ short f2bf(float v) {
    unsigned u = __builtin_bit_cast(unsigned, v);
    u += 0x7fffu + ((u >> 16) & 1u);  // RNE (finite values only)
    return (short)(u >> 16);
}

// ---------------- prep: x, x0, h = (feat*nm)@emb_w + emb_b ----------------
__global__ void prep_kernel(const float* __restrict__ xh, const float* __restrict__ nm,
                            const float* __restrict__ emb_w, const float* __restrict__ emb_b,
                            float* __restrict__ x, float* __restrict__ x0, float* __restrict__ h) {
    const int v = blockIdx.x;
    const int t = threadIdx.x;  // 128
    const float m = nm[v];
    __shared__ float f[INNF];
    if (t < INNF) f[t] = xh[v * (DD + INNF) + DD + t] * m;
    if (t < DD) {
        float c = xh[v * (DD + INNF) + t] * m;
        x[v * DD + t] = c;
        x0[v * DD + t] = c;
    }
    __syncthreads();
    float acc = emb_b[t];
#pragma unroll
    for (int k = 0; k < INNF; ++k) acc = fmaf(f[k], emb_w[k * HH + t], acc);
    h[v * HH + t] = acc;
}

// ---------------- weight prep: bf16 transposed (K-contiguous per column) ----------------
__global__ void wprep_kernel(const float* __restrict__ ew2, const float* __restrict__ cw1,
                             short* __restrict__ ew2T, short* __restrict__ cw1T) {
    const int l = blockIdx.x >> 1, which = blockIdx.x & 1;
    const float* src = (which ? cw1 : ew2) + (size_t)l * HH * HH;
    short* dst = (which ? cw1T : ew2T) + (size_t)l * HH * HH;
    for (int idx = threadIdx.x; idx < HH * HH; idx += blockDim.x) {
        const int k = idx >> 7, c = idx & 127;
        dst[c * HH + k] = f2bf(src[idx]);
    }
}

// ---------------- per-layer: P = h@Wr + eb1, Q = h@Wc ----------------
__global__ __launch_bounds__(256) void pq_kernel(const float* __restrict__ h,
                                                 const float* __restrict__ ew1l,
                                                 const float* __restrict__ eb1l,
                                                 float* __restrict__ P, float* __restrict__ Q) {
    const int v = blockIdx.x;
    const int t = threadIdx.x;  // 256
    __shared__ float shh[HH];
    if (t < HH) shh[t] = h[v * HH + t];
    __syncthreads();
    const int c = t & (HH - 1);
    const int which = t >> 7;  // 0: P, 1: Q
    const float* W = ew1l + which * HH * HH;
    float acc = which ? 0.0f : eb1l[c];
#pragma unroll 8
    for (int k = 0; k < HH; ++k) acc = fmaf(shh[k], W[k * HH + c], acc);
    if (which) Q[v * HH + c] = acc;
    else P[v * HH + c] = acc;
}

// ---------------- per-layer edge kernel: one block per row-node ----------------
__global__ __launch_bounds__(256) void edge_kernel(
    const float* __restrict__ P, const float* __restrict__ Q,
    const float* __restrict__ x, const float* __restrict__ x0,
    const float* __restrict__ em,
    const float* __restrict__ ew1l,   // [258][128] (rows 256,257 used)
    const short* __restrict__ ew2T,   // [128 cols][128 k] bf16
    const float* __restrict__ eb2l,
    const short* __restrict__ cw1T,   // [128 cols][128 k] bf16
    const float* __restrict__ cb1l,
    const float* __restrict__ cw2l,
    float* __restrict__ x_out, float* __restrict__ agg) {

    const int r = blockIdx.x;
    const int i = r & (NN - 1);
    const int g0 = r & ~(NN - 1);
    const int t = threadIdx.x;       // 256
    const int w = t >> 6;            // wave 0..3
    const int l = t & 63;
    const int l15 = l & 15, l4 = l >> 4;

    __shared__ __align__(16) char shAc[NN * 256];   // [64 rows][128 bf16], swizzled (16 KB)
    __shared__ float shP[HH], shw256[HH], shw257[HH];
    __shared__ float shEb2[HH], shCb1[HH], shCw2[HH];
    __shared__ float shx[NN * 3], shx0g[NN * 3];
    __shared__ float shrad[NN], shea[NN], shem[NN], shcdn[NN * 3], shphi[NN];
    __shared__ float shagg[4 * HH];

    if (t < HH) {
        shP[t] = P[r * HH + t];
        shw256[t] = ew1l[256 * HH + t];
        shw257[t] = ew1l[257 * HH + t];
        shEb2[t] = eb2l[t];
        shCb1[t] = cb1l[t];
        shCw2[t] = cw2l[t];
    }
    if (t < NN * 3) {  // FIX (R2 bug): full 192-entry range, not t-HH
        shx[t] = x[g0 * 3 + t];
        shx0g[t] = x0[g0 * 3 + t];
    }
    __syncthreads();
    if (t < NN) {
        const int j = t;
        float dx = shx[i * 3 + 0] - shx[j * 3 + 0];
        float dy = shx[i * 3 + 1] - shx[j * 3 + 1];
        float dz = shx[i * 3 + 2] - shx[j * 3 + 2];
        float rad = dx * dx + dy * dy + dz * dz;
        shrad[j] = rad;
        float inv = 1.0f / (sqrtf(rad + 1e-8f) + 1.0f);
        shcdn[j * 3 + 0] = dx * inv;
        shcdn[j * 3 + 1] = dy * inv;
        shcdn[j * 3 + 2] = dz * inv;
        float ex = shx0g[i * 3 + 0] - shx0g[j * 3 + 0];
        float ey = shx0g[i * 3 + 1] - shx0g[j * 3 + 1];
        float ez = shx0g[i * 3 + 2] - shx0g[j * 3 + 2];
        shea[j] = ex * ex + ey * ey + ez * ez;
        shem[j] = em[r * NN + j];
    }
    __syncthreads();

    // ---- build t1 rows (wave-private: wave w builds rows [w*16, w*16+16)) ----
    {
        const int j = t >> 2;                 // row (edge)
        const float rad = shrad[j], ea = shea[j];
#pragma unroll
        for (int p = 0; p < 4; ++p) {
            const int k0 = (t & 3) * 8 + p * 32;
            const float4 qa = *(const float4*)(Q + (size_t)(g0 + j) * HH + k0);
            const float4 qb = *(const float4*)(Q + (size_t)(g0 + j) * HH + k0 + 4);
            const float qv[8] = {qa.x, qa.y, qa.z, qa.w, qb.x, qb.y, qb.z, qb.w};
            bf16x8 s;
#pragma unroll
            for (int u = 0; u < 8; ++u) {
                const int k = k0 + u;
                float v = shP[k] + qv[u] + rad * shw256[k] + ea * shw257[k];
                s[u] = f2bf(silu_f(v));
            }
            const int byte = j * 256 + ((k0 * 2) ^ ((j & 7) << 4));
            *(bf16x8*)(shAc + byte) = s;
        }
    }

    const int arow = w * 16 + l15;
    const int abase = arow * 256;
    const int axor = (arow & 7) << 4;

    // ---- GEMM2: m = silu(t1 @ ew2 + eb2) * em ----
    f32x4 acc[8];
#pragma unroll
    for (int ct = 0; ct < 8; ++ct) acc[ct] = (f32x4){0.f, 0.f, 0.f, 0.f};
    {
        bf16x8 af[4];
#pragma unroll
        for (int kt = 0; kt < 4; ++kt)
            af[kt] = *(const bf16x8*)(shAc + abase + (((kt * 4 + l4) * 16) ^ axor));
#pragma unroll
        for (int ct = 0; ct < 8; ++ct) {
#pragma unroll
            for (int kt = 0; kt < 4; ++kt) {
                const bf16x8 bf = *(const bf16x8*)(ew2T + (size_t)(ct * 16 + l15) * HH + kt * 32 + l4 * 8);
                acc[ct] = __builtin_amdgcn_mfma_f32_16x16x32_bf16(af[kt], bf, acc[ct], 0, 0, 0);
            }
        }
    }
    // epilogue: silu+mask, write m (bf16, swizzled, wave-private rows), agg partials
#pragma unroll
    for (int ct = 0; ct < 8; ++ct) {
        const int c = ct * 16 + l15;
        const float b = shEb2[c];
        float pagg = 0.0f;
#pragma unroll
        for (int reg = 0; reg < 4; ++reg) {
            const int row = w * 16 + l4 * 4 + reg;
            float v = silu_f(acc[ct][reg] + b) * shem[row];
            pagg += v;
            const int byte = row * 256 + ((c * 2) ^ ((row & 7) << 4));
            *(short*)(shAc + byte) = f2bf(v);
        }
        pagg += __shfl_xor(pagg, 16);
        pagg += __shfl_xor(pagg, 32);
        if (l4 == 0) shagg[w * HH + c] = pagg;  // wave-partial column sum
    }

    // ---- GEMM3: c1 = m @ cw1 ----
#pragma unroll
    for (int ct = 0; ct < 8; ++ct) acc[ct] = (f32x4){0.f, 0.f, 0.f, 0.f};
    {
        bf16x8 af[4];
#pragma unroll
        for (int kt = 0; kt < 4; ++kt)
            af[kt] = *(const bf16x8*)(shAc + abase + (((kt * 4 + l4) * 16) ^ axor));
#pragma unroll
        for (int ct = 0; ct < 8; ++ct) {
#pragma unroll
            for (int kt = 0; kt < 4; ++kt) {
                const bf16x8 bf = *(const bf16x8*)(cw1T + (size_t)(ct * 16 + l15) * HH + kt * 32 + l4 * 8);
                acc[ct] = __builtin_amdgcn_mfma_f32_16x16x32_bf16(af[kt], bf, acc[ct], 0, 0, 0);
            }
        }
    }
    // epilogue: phi[row] = sum_c silu(c1+cb1)*cw2
    {
        float pp[4] = {0.f, 0.f, 0.f, 0.f};
#pragma unroll
        for (int ct = 0; ct < 8; ++ct) {
            const int c = ct * 16 + l15;
            const float cb = shCb1[c], cw = shCw2[c];
#pragma unroll
            for (int reg = 0; reg < 4; ++reg) {
                float v = silu_f(acc[ct][reg] + cb);
                pp[reg] = fmaf(v, cw, pp[reg]);
            }
        }
#pragma unroll
        for (int off = 8; off >= 1; off >>= 1) {
#pragma unroll
            for (int reg = 0; reg < 4; ++reg) pp[reg] += __shfl_xor(pp[reg], off);
        }
        if (l15 == 0) {
#pragma unroll
            for (int reg = 0; reg < 4; ++reg) shphi[w * 16 + l4 * 4 + reg] = pp[reg];
        }
    }
    __syncthreads();

    // x_out[r] = x[r] + sum_j cdn[j]*phi[j]*em[j]  (3 waves, one per coord)
    if (t < 192) {
        const int q = t >> 6, j = t & 63;
        float v = shcdn[j * 3 + q] * shphi[j] * shem[j];
#pragma unroll
        for (int off = 32; off >= 1; off >>= 1) v += __shfl_xor(v, off);
        if (j == 0) x_out[r * 3 + q] = shx[i * 3 + q] + v;
    }
    if (t < HH) {
        agg[r * HH + t] = shagg[0 * HH + t] + shagg[1 * HH + t] + shagg[2 * HH + t] + shagg[3 * HH + t];
    }
}

// ---------------- per-layer node update (in place) ----------------
__global__ void node_kernel(float* __restrict__ h, const float* __restrict__ agg,
                            const float* __restrict__ nm,
                            const float* __restrict__ nw1l, const float* __restrict__ nb1l,
                            const float* __restrict__ nw2l, const float* __restrict__ nb2l) {
    const int v = blockIdx.x;
    const int t = threadIdx.x;  // 128
    __shared__ float shh[HH], sha[HH], sht[HH];
    shh[t] = h[v * HH + t];
    sha[t] = agg[v * HH + t];
    __syncthreads();
    float acc = nb1l[t];
#pragma unroll 8
    for (int k = 0; k < HH; ++k) acc = fmaf(shh[k], nw1l[k * HH + t], acc);
#pragma unroll 8
    for (int k = 0; k < HH; ++k) acc = fmaf(sha[k], nw1l[(HH + k) * HH + t], acc);
    sht[t] = silu_f(acc);
    __syncthreads();
    float d = nb2l[t];
#pragma unroll 8
    for (int k = 0; k < HH; ++k) d = fmaf(sht[k], nw2l[k * HH + t], d);
    h[v * HH + t] = (shh[t] + d) * nm[v];
}

// ---------------- output: per-graph mean of (h@out_w + out_b)*nm ----------------
__global__ void out_kernel(const float* __restrict__ h, const float* __restrict__ nm,
                           const float* __restrict__ ow, const float* __restrict__ ob,
                           float* __restrict__ out) {
    const int b = blockIdx.x;
    const int n = threadIdx.x;  // 64
    const int v = b * NN + n;
    float acc = 0.0f;
#pragma unroll 8
    for (int c = 0; c < HH; ++c) acc = fmaf(h[v * HH + c], ow[c], acc);
    acc = (acc + ob[0]) * nm[v];
#pragma unroll
    for (int off = 32; off >= 1; off >>= 1) acc += __shfl_xor(acc, off);
    if (n == 0) out[b] = acc * (1.0f / (float)NN);
}

extern "C" void kernel_launch(void* const* d_in, const int* in_sizes, int n_in,
                              void* d_out, int out_size, void* d_ws, size_t ws_size,
                              hipStream_t stream) {
    const float* xh    = (const float*)d_in[0];
    const float* nmask = (const float*)d_in[1];
    const float* emask = (const float*)d_in[2];
    const float* emb_w = (const float*)d_in[3];
    const float* emb_b = (const float*)d_in[4];
    const float* out_w = (const float*)d_in[5];
    const float* out_b = (const float*)d_in[6];
    const float* ew1   = (const float*)d_in[7];
    const float* eb1   = (const float*)d_in[8];
    const float* ew2   = (const float*)d_in[9];
    const float* eb2   = (const float*)d_in[10];
    const float* nw1   = (const float*)d_in[11];
    const float* nb1   = (const float*)d_in[12];
    const float* nw2   = (const float*)d_in[13];
    const float* nb2   = (const float*)d_in[14];
    const float* cw1   = (const float*)d_in[15];
    const float* cb1   = (const float*)d_in[16];
    const float* cw2   = (const float*)d_in[17];

    float* ws  = (float*)d_ws;
    float* xA  = ws;                    // [4096*3]
    float* xB  = xA + BNODES * 3;       // [4096*3]
    float* x0  = xB + BNODES * 3;       // [4096*3]
    float* h   = x0 + BNODES * 3;       // [4096*128]
    float* Pb  = h + BNODES * HH;       // [4096*128]
    float* Qb  = Pb + BNODES * HH;      // [4096*128]
    float* agg = Qb + BNODES * HH;      // [4096*128]
    short* ew2T = (short*)(agg + BNODES * HH);  // [4][128*128] bf16
    short* cw1T = ew2T + LL * HH * HH;          // [4][128*128] bf16

    prep_kernel<<<BNODES, HH, 0, stream>>>(xh, nmask, emb_w, emb_b, xA, x0, h);
    wprep_kernel<<<2 * LL, 256, 0, stream>>>(ew2, cw1, ew2T, cw1T);

    float* xc = xA;
    float* xn = xB;
    for (int l = 0; l < LL; ++l) {
        const float* ew1l = ew1 + (size_t)l * 258 * HH;
        pq_kernel<<<BNODES, 256, 0, stream>>>(h, ew1l, eb1 + l * HH, Pb, Qb);
        edge_kernel<<<BNODES, 256, 0, stream>>>(Pb, Qb, xc, x0, emask, ew1l,
                                                ew2T + (size_t)l * HH * HH, eb2 + l * HH,
                                                cw1T + (size_t)l * HH * HH, cb1 + l * HH,
                                                cw2 + (size_t)l * HH, xn, agg);
        node_kernel<<<BNODES, HH, 0, stream>>>(h, agg, nmask,
                                               nw1 + (size_t)l * 2 * HH * HH, nb1 + l * HH,
                                               nw2 + (size_t)l * HH * HH, nb2 + l * HH);
        float* tmp = xc; xc = xn; xn = tmp;
    }

    out_kernel<<<NB, NN, 0, stream>>>(h, nmask, out_w, out_b, (float*)d_out);
}

// Round 4
// 435.146 us; speedup vs baseline: 2.9220x; 1.6173x over previous
//
#include <hip/hip_runtime.h>
#include <math.h>

// EGNN: B=64 graphs x N=64 nodes, D=3, IN_NF=8, H=128, L=4 layers.
// e_in @ ew1 = P[row] + Q[col] + radial*w256 + ea*w257 (per-node GEMMs).
// Edge kernel R3: col-sliced waves (wave w owns cols w*32..w*32+32, all 64
// rows) -> 4x less B traffic; B double-buffered from L2; agg reduced fully
// in-wave; phi via 4-way cross-wave partials in LDS.

#define NB 64
#define NN 64
#define DD 3
#define INNF 8
#define HH 128
#define LL 4
#define BNODES (NB * NN)  // 4096

typedef __attribute__((ext_vector_type(8))) short bf16x8;
typedef __attribute__((ext_vector_type(4))) float f32x4;

__device__ __forceinline__ float silu_f(float v) {
    float e = __expf(-v);
    return v * __builtin_amdgcn_rcpf(1.0f + e);
}

__device__ __forceinline__ short f2bf(float v) {
    unsigned u = __builtin_bit_cast(unsigned, v);
    u += 0x7fffu + ((u >> 16) & 1u);  // RNE (finite values only)
    return (short)(u >> 16);
}

// ---------------- prep: x, x0, h = (feat*nm)@emb_w + emb_b ----------------
__global__ void prep_kernel(const float* __restrict__ xh, const float* __restrict__ nm,
                            const float* __restrict__ emb_w, const float* __restrict__ emb_b,
                            float* __restrict__ x, float* __restrict__ x0, float* __restrict__ h) {
    const int v = blockIdx.x;
    const int t = threadIdx.x;  // 128
    const float m = nm[v];
    __shared__ float f[INNF];
    if (t < INNF) f[t] = xh[v * (DD + INNF) + DD + t] * m;
    if (t < DD) {
        float c = xh[v * (DD + INNF) + t] * m;
        x[v * DD + t] = c;
        x0[v * DD + t] = c;
    }
    __syncthreads();
    float acc = emb_b[t];
#pragma unroll
    for (int k = 0; k < INNF; ++k) acc = fmaf(f[k], emb_w[k * HH + t], acc);
    h[v * HH + t] = acc;
}

// ---------------- weight prep: bf16 transposed (K-contiguous per column) ----------------
__global__ void wprep_kernel(const float* __restrict__ ew2, const float* __restrict__ cw1,
                             short* __restrict__ ew2T, short* __restrict__ cw1T) {
    const int l = blockIdx.x >> 1, which = blockIdx.x & 1;
    const float* src = (which ? cw1 : ew2) + (size_t)l * HH * HH;
    short* dst = (which ? cw1T : ew2T) + (size_t)l * HH * HH;
    for (int idx = threadIdx.x; idx < HH * HH; idx += blockDim.x) {
        const int k = idx >> 7, c = idx & 127;
        dst[c * HH + k] = f2bf(src[idx]);
    }
}

// ---------------- per-layer: P = h@Wr + eb1, Q = h@Wc ----------------
__global__ __launch_bounds__(256) void pq_kernel(const float* __restrict__ h,
                                                 const float* __restrict__ ew1l,
                                                 const float* __restrict__ eb1l,
                                                 float* __restrict__ P, float* __restrict__ Q) {
    const int v = blockIdx.x;
    const int t = threadIdx.x;  // 256
    __shared__ float shh[HH];
    if (t < HH) shh[t] = h[v * HH + t];
    __syncthreads();
    const int c = t & (HH - 1);
    const int which = t >> 7;  // 0: P, 1: Q
    const float* W = ew1l + which * HH * HH;
    float acc = which ? 0.0f : eb1l[c];
#pragma unroll 8
    for (int k = 0; k < HH; ++k) acc = fmaf(shh[k], W[k * HH + c], acc);
    if (which) Q[v * HH + c] = acc;
    else P[v * HH + c] = acc;
}

// ---------------- per-layer edge kernel: one block per row-node ----------------
__global__ __launch_bounds__(256) void edge_kernel(
    const float* __restrict__ P, const float* __restrict__ Q,
    const float* __restrict__ x, const float* __restrict__ x0,
    const float* __restrict__ em,
    const float* __restrict__ ew1l,   // [258][128] (rows 256,257 used)
    const short* __restrict__ ew2T,   // [128 cols][128 k] bf16
    const float* __restrict__ eb2l,
    const short* __restrict__ cw1T,   // [128 cols][128 k] bf16
    const float* __restrict__ cb1l,
    const float* __restrict__ cw2l,
    float* __restrict__ x_out, float* __restrict__ agg) {

    const int r = blockIdx.x;
    const int i = r & (NN - 1);
    const int g0 = r & ~(NN - 1);
    const int t = threadIdx.x;       // 256
    const int w = t >> 6;            // wave 0..3
    const int l = t & 63;
    const int l15 = l & 15, l4 = l >> 4;
    const int c0 = w * 32;           // wave's column base

    __shared__ __align__(16) char shAc[NN * 256];   // [64 rows][128 bf16], swizzled (16 KB)
    __shared__ float shP[HH], shw256[HH], shw257[HH];
    __shared__ float shEb2[HH], shCb1[HH], shCw2[HH];
    __shared__ float shx[NN * 3], shx0g[NN * 3];
    __shared__ float shrad[NN], shea[NN], shem[NN], shcdn[NN * 3];
    __shared__ float shphiP[4][NN];

    if (t < HH) {
        shP[t] = P[r * HH + t];
        shw256[t] = ew1l[256 * HH + t];
        shw257[t] = ew1l[257 * HH + t];
        shEb2[t] = eb2l[t];
        shCb1[t] = cb1l[t];
        shCw2[t] = cw2l[t];
    }
    if (t < NN * 3) {
        shx[t] = x[g0 * 3 + t];
        shx0g[t] = x0[g0 * 3 + t];
    }
    __syncthreads();
    if (t < NN) {
        const int j = t;
        float dx = shx[i * 3 + 0] - shx[j * 3 + 0];
        float dy = shx[i * 3 + 1] - shx[j * 3 + 1];
        float dz = shx[i * 3 + 2] - shx[j * 3 + 2];
        float rad = dx * dx + dy * dy + dz * dz;
        shrad[j] = rad;
        float inv = 1.0f / (sqrtf(rad + 1e-8f) + 1.0f);
        shcdn[j * 3 + 0] = dx * inv;
        shcdn[j * 3 + 1] = dy * inv;
        shcdn[j * 3 + 2] = dz * inv;
        float ex = shx0g[i * 3 + 0] - shx0g[j * 3 + 0];
        float ey = shx0g[i * 3 + 1] - shx0g[j * 3 + 1];
        float ez = shx0g[i * 3 + 2] - shx0g[j * 3 + 2];
        shea[j] = ex * ex + ey * ey + ez * ez;
        shem[j] = em[r * NN + j];
    }
    __syncthreads();

    // ---- build t1 rows: thread t builds row t>>2, k-chunks (t&3)*8 + p*32 ----
    {
        const int j = t >> 2;
        const float rad = shrad[j], ea = shea[j];
#pragma unroll
        for (int p = 0; p < 4; ++p) {
            const int k0 = (t & 3) * 8 + p * 32;
            const float4 qa = *(const float4*)(Q + (size_t)(g0 + j) * HH + k0);
            const float4 qb = *(const float4*)(Q + (size_t)(g0 + j) * HH + k0 + 4);
            const float qv[8] = {qa.x, qa.y, qa.z, qa.w, qb.x, qb.y, qb.z, qb.w};
            bf16x8 s;
#pragma unroll
            for (int u = 0; u < 8; ++u) {
                const int k = k0 + u;
                float v = shP[k] + qv[u] + rad * shw256[k] + ea * shw257[k];
                s[u] = f2bf(silu_f(v));
            }
            const int byte = j * 256 + ((k0 * 2) ^ ((j & 7) << 4));
            *(bf16x8*)(shAc + byte) = s;
        }
    }
    __syncthreads();  // cross-wave A reads below

    // ---- GEMM2: m = silu(t1 @ ew2 + eb2) * em  (col-sliced, B double-buffered) ----
    f32x4 acc[4][2];  // [row-tile][col-tile]
#pragma unroll
    for (int rt = 0; rt < 4; ++rt) {
        acc[rt][0] = (f32x4){0.f, 0.f, 0.f, 0.f};
        acc[rt][1] = (f32x4){0.f, 0.f, 0.f, 0.f};
    }
    {
        const short* B2 = ew2T + (size_t)(c0 + l15) * HH + l4 * 8;
        bf16x8 bcur[2], bnxt[2];
        bcur[0] = *(const bf16x8*)(B2);
        bcur[1] = *(const bf16x8*)(B2 + 16 * HH);
#pragma unroll
        for (int kt = 0; kt < 4; ++kt) {
            if (kt < 3) {
                bnxt[0] = *(const bf16x8*)(B2 + (kt + 1) * 32);
                bnxt[1] = *(const bf16x8*)(B2 + 16 * HH + (kt + 1) * 32);
            }
            bf16x8 af[4];
#pragma unroll
            for (int rt = 0; rt < 4; ++rt) {
                const int row = rt * 16 + l15;
                af[rt] = *(const bf16x8*)(shAc + row * 256 + (((kt * 4 + l4) * 16) ^ ((row & 7) << 4)));
            }
#pragma unroll
            for (int rt = 0; rt < 4; ++rt) {
                acc[rt][0] = __builtin_amdgcn_mfma_f32_16x16x32_bf16(af[rt], bcur[0], acc[rt][0], 0, 0, 0);
                acc[rt][1] = __builtin_amdgcn_mfma_f32_16x16x32_bf16(af[rt], bcur[1], acc[rt][1], 0, 0, 0);
            }
            bcur[0] = bnxt[0];
            bcur[1] = bnxt[1];
        }
    }
    __syncthreads();  // GEMM2 A-reads done before m overwrites shAc

    // epilogue: m = silu(acc+eb2)*em -> shAc (swizzled); agg fully in-wave
#pragma unroll
    for (int ct2 = 0; ct2 < 2; ++ct2) {
        const int c = c0 + ct2 * 16 + l15;
        const float b = shEb2[c];
        float pagg = 0.0f;
#pragma unroll
        for (int rt = 0; rt < 4; ++rt) {
#pragma unroll
            for (int reg = 0; reg < 4; ++reg) {
                const int row = rt * 16 + l4 * 4 + reg;
                float v = silu_f(acc[rt][ct2][reg] + b) * shem[row];
                pagg += v;
                const int byte = row * 256 + ((c * 2) ^ ((row & 7) << 4));
                *(short*)(shAc + byte) = f2bf(v);
            }
        }
        pagg += __shfl_xor(pagg, 16);
        pagg += __shfl_xor(pagg, 32);
        if (l4 == 0) agg[r * HH + c] = pagg;
    }
    __syncthreads();  // m complete before GEMM3 cross-wave A reads

    // ---- GEMM3: c1 = m @ cw1 ----
#pragma unroll
    for (int rt = 0; rt < 4; ++rt) {
        acc[rt][0] = (f32x4){0.f, 0.f, 0.f, 0.f};
        acc[rt][1] = (f32x4){0.f, 0.f, 0.f, 0.f};
    }
    {
        const short* B3 = cw1T + (size_t)(c0 + l15) * HH + l4 * 8;
        bf16x8 bcur[2], bnxt[2];
        bcur[0] = *(const bf16x8*)(B3);
        bcur[1] = *(const bf16x8*)(B3 + 16 * HH);
#pragma unroll
        for (int kt = 0; kt < 4; ++kt) {
            if (kt < 3) {
                bnxt[0] = *(const bf16x8*)(B3 + (kt + 1) * 32);
                bnxt[1] = *(const bf16x8*)(B3 + 16 * HH + (kt + 1) * 32);
            }
            bf16x8 af[4];
#pragma unroll
            for (int rt = 0; rt < 4; ++rt) {
                const int row = rt * 16 + l15;
                af[rt] = *(const bf16x8*)(shAc + row * 256 + (((kt * 4 + l4) * 16) ^ ((row & 7) << 4)));
            }
#pragma unroll
            for (int rt = 0; rt < 4; ++rt) {
                acc[rt][0] = __builtin_amdgcn_mfma_f32_16x16x32_bf16(af[rt], bcur[0], acc[rt][0], 0, 0, 0);
                acc[rt][1] = __builtin_amdgcn_mfma_f32_16x16x32_bf16(af[rt], bcur[1], acc[rt][1], 0, 0, 0);
            }
            bcur[0] = bnxt[0];
            bcur[1] = bnxt[1];
        }
    }

    // epilogue: phi partials (wave covers its 32 cols), reduce over l15
    {
        float pp[4][4];
#pragma unroll
        for (int rt = 0; rt < 4; ++rt)
#pragma unroll
            for (int reg = 0; reg < 4; ++reg) pp[rt][reg] = 0.0f;
#pragma unroll
        for (int ct2 = 0; ct2 < 2; ++ct2) {
            const int c = c0 + ct2 * 16 + l15;
            const float cb = shCb1[c], cw = shCw2[c];
#pragma unroll
            for (int rt = 0; rt < 4; ++rt) {
#pragma unroll
                for (int reg = 0; reg < 4; ++reg) {
                    float v = silu_f(acc[rt][ct2][reg] + cb);
                    pp[rt][reg] = fmaf(v, cw, pp[rt][reg]);
                }
            }
        }
#pragma unroll
        for (int off = 8; off >= 1; off >>= 1) {
#pragma unroll
            for (int rt = 0; rt < 4; ++rt)
#pragma unroll
                for (int reg = 0; reg < 4; ++reg) pp[rt][reg] += __shfl_xor(pp[rt][reg], off);
        }
        if (l15 == 0) {
#pragma unroll
            for (int rt = 0; rt < 4; ++rt)
#pragma unroll
                for (int reg = 0; reg < 4; ++reg)
                    shphiP[w][rt * 16 + l4 * 4 + reg] = pp[rt][reg];
        }
    }
    __syncthreads();

    // x_out[r] = x[r] + sum_j cdn[j]*phi[j]*em[j]  (3 waves, one per coord)
    if (t < 192) {
        const int q = t >> 6, j = t & 63;
        const float phi = shphiP[0][j] + shphiP[1][j] + shphiP[2][j] + shphiP[3][j];
        float v = shcdn[j * 3 + q] * phi * shem[j];
#pragma unroll
        for (int off = 32; off >= 1; off >>= 1) v += __shfl_xor(v, off);
        if (j == 0) x_out[r * 3 + q] = shx[i * 3 + q] + v;
    }
}

// ---------------- per-layer node update (in place) ----------------
__global__ void node_kernel(float* __restrict__ h, const float* __restrict__ agg,
                            const float* __restrict__ nm,
                            const float* __restrict__ nw1l, const float* __restrict__ nb1l,
                            const float* __restrict__ nw2l, const float* __restrict__ nb2l) {
    const int v = blockIdx.x;
    const int t = threadIdx.x;  // 128
    __shared__ float shh[HH], sha[HH], sht[HH];
    shh[t] = h[v * HH + t];
    sha[t] = agg[v * HH + t];
    __syncthreads();
    float acc = nb1l[t];
#pragma unroll 8
    for (int k = 0; k < HH; ++k) acc = fmaf(shh[k], nw1l[k * HH + t], acc);
#pragma unroll 8
    for (int k = 0; k < HH; ++k) acc = fmaf(sha[k], nw1l[(HH + k) * HH + t], acc);
    sht[t] = silu_f(acc);
    __syncthreads();
    float d = nb2l[t];
#pragma unroll 8
    for (int k = 0; k < HH; ++k) d = fmaf(sht[k], nw2l[k * HH + t], d);
    h[v * HH + t] = (shh[t] + d) * nm[v];
}

// ---------------- output: per-graph mean of (h@out_w + out_b)*nm ----------------
__global__ void out_kernel(const float* __restrict__ h, const float* __restrict__ nm,
                           const float* __restrict__ ow, const float* __restrict__ ob,
                           float* __restrict__ out) {
    const int b = blockIdx.x;
    const int n = threadIdx.x;  // 64
    const int v = b * NN + n;
    float acc = 0.0f;
#pragma unroll 8
    for (int c = 0; c < HH; ++c) acc = fmaf(h[v * HH + c], ow[c], acc);
    acc = (acc + ob[0]) * nm[v];
#pragma unroll
    for (int off = 32; off >= 1; off >>= 1) acc += __shfl_xor(acc, off);
    if (n == 0) out[b] = acc * (1.0f / (float)NN);
}

extern "C" void kernel_launch(void* const* d_in, const int* in_sizes, int n_in,
                              void* d_out, int out_size, void* d_ws, size_t ws_size,
                              hipStream_t stream) {
    const float* xh    = (const float*)d_in[0];
    const float* nmask = (const float*)d_in[1];
    const float* emask = (const float*)d_in[2];
    const float* emb_w = (const float*)d_in[3];
    const float* emb_b = (const float*)d_in[4];
    const float* out_w = (const float*)d_in[5];
    const float* out_b = (const float*)d_in[6];
    const float* ew1   = (const float*)d_in[7];
    const float* eb1   = (const float*)d_in[8];
    const float* ew2   = (const float*)d_in[9];
    const float* eb2   = (const float*)d_in[10];
    const float* nw1   = (const float*)d_in[11];
    const float* nb1   = (const float*)d_in[12];
    const float* nw2   = (const float*)d_in[13];
    const float* nb2   = (const float*)d_in[14];
    const float* cw1   = (const float*)d_in[15];
    const float* cb1   = (const float*)d_in[16];
    const float* cw2   = (const float*)d_in[17];

    float* ws  = (float*)d_ws;
    float* xA  = ws;                    // [4096*3]
    float* xB  = xA + BNODES * 3;       // [4096*3]
    float* x0  = xB + BNODES * 3;       // [4096*3]
    float* h   = x0 + BNODES * 3;       // [4096*128]
    float* Pb  = h + BNODES * HH;       // [4096*128]
    float* Qb  = Pb + BNODES * HH;      // [4096*128]
    float* agg = Qb + BNODES * HH;      // [4096*128]
    short* ew2T = (short*)(agg + BNODES * HH);  // [4][128*128] bf16
    short* cw1T = ew2T + LL * HH * HH;          // [4][128*128] bf16

    prep_kernel<<<BNODES, HH, 0, stream>>>(xh, nmask, emb_w, emb_b, xA, x0, h);
    wprep_kernel<<<2 * LL, 256, 0, stream>>>(ew2, cw1, ew2T, cw1T);

    float* xc = xA;
    float* xn = xB;
    for (int l = 0; l < LL; ++l) {
        const float* ew1l = ew1 + (size_t)l * 258 * HH;
        pq_kernel<<<BNODES, 256, 0, stream>>>(h, ew1l, eb1 + l * HH, Pb, Qb);
        edge_kernel<<<BNODES, 256, 0, stream>>>(Pb, Qb, xc, x0, emask, ew1l,
                                                ew2T + (size_t)l * HH * HH, eb2 + l * HH,
                                                cw1T + (size_t)l * HH * HH, cb1 + l * HH,
                                                cw2 + (size_t)l * HH, xn, agg);
        node_kernel<<<BNODES, HH, 0, stream>>>(h, agg, nmask,
                                               nw1 + (size_t)l * 2 * HH * HH, nb1 + l * HH,
                                               nw2 + (size_t)l * HH * HH, nb2 + l * HH);
        float* tmp = xc; xc = xn; xn = tmp;
    }

    out_kernel<<<NB, NN, 0, stream>>>(h, nmask, out_w, out_b, (float*)d_out);
}

// Round 5
// 352.461 us; speedup vs baseline: 3.6075x; 1.2346x over previous
//
#include <hip/hip_runtime.h>
#include <math.h>

// EGNN: B=64 graphs x N=64 nodes, D=3, IN_NF=8, H=128, L=4 layers.
// e_in @ ew1 = P[row] + Q[col] + radial*w256 + ea*w257 (per-node GEMMs).
// R4: pq/node kernels converted to bf16 MFMA tiles (16 nodes/block, weights
// read once per block); edge kernel uses native __bf16 casts (cvt_pk fusion).

#define NB 64
#define NN 64
#define DD 3
#define INNF 8
#define HH 128
#define LL 4
#define BNODES (NB * NN)  // 4096

typedef __attribute__((ext_vector_type(8))) short bf16x8;
typedef __attribute__((ext_vector_type(4))) float f32x4;

__device__ __forceinline__ float silu_f(float v) {
    float e = __expf(-v);
    return v * __builtin_amdgcn_rcpf(1.0f + e);
}

__device__ __forceinline__ short f2bf(float v) {
    __bf16 b = (__bf16)v;  // native cast -> compiler pairs into v_cvt_pk_bf16_f32
    return __builtin_bit_cast(short, b);
}

// ---------------- prep: x, x0, h = (feat*nm)@emb_w + emb_b ----------------
__global__ void prep_kernel(const float* __restrict__ xh, const float* __restrict__ nm,
                            const float* __restrict__ emb_w, const float* __restrict__ emb_b,
                            float* __restrict__ x, float* __restrict__ x0, float* __restrict__ h) {
    const int v = blockIdx.x;
    const int t = threadIdx.x;  // 128
    const float m = nm[v];
    __shared__ float f[INNF];
    if (t < INNF) f[t] = xh[v * (DD + INNF) + DD + t] * m;
    if (t < DD) {
        float c = xh[v * (DD + INNF) + t] * m;
        x[v * DD + t] = c;
        x0[v * DD + t] = c;
    }
    __syncthreads();
    float acc = emb_b[t];
#pragma unroll
    for (int k = 0; k < INNF; ++k) acc = fmaf(f[k], emb_w[k * HH + t], acc);
    h[v * HH + t] = acc;
}

// ---------------- weight prep: bf16, K-contiguous per output column ----------------
__global__ void wprep_kernel(const float* __restrict__ ew1, const float* __restrict__ ew2,
                             const float* __restrict__ cw1, const float* __restrict__ nw1,
                             const float* __restrict__ nw2,
                             short* __restrict__ ew1T, short* __restrict__ ew2T,
                             short* __restrict__ cw1T, short* __restrict__ nw1T,
                             short* __restrict__ nw2T) {
    const int l = blockIdx.x / 5, which = blockIdx.x % 5;
    if (which == 0) {
        // ew1T[c'][k], c' in [0,256): c'<128 -> Wr rows 0..127, else Wc rows 128..255
        const float* src = ew1 + (size_t)l * 258 * HH;
        short* dst = ew1T + (size_t)l * 256 * HH;
        for (int idx = threadIdx.x; idx < 256 * HH; idx += blockDim.x) {
            const int cp = idx >> 7, k = idx & 127;
            dst[cp * HH + k] = f2bf(src[(k + ((cp >> 7) << 7)) * HH + (cp & 127)]);
        }
    } else if (which == 3) {
        // nw1T[c][k], k in [0,256)
        const float* src = nw1 + (size_t)l * 2 * HH * HH;
        short* dst = nw1T + (size_t)l * 2 * HH * HH;
        for (int idx = threadIdx.x; idx < 2 * HH * HH; idx += blockDim.x) {
            const int c = idx >> 8, k = idx & 255;
            dst[c * 256 + k] = f2bf(src[k * HH + c]);
        }
    } else {
        const float* src = (which == 1 ? ew2 : which == 2 ? cw1 : nw2) + (size_t)l * HH * HH;
        short* dst = (which == 1 ? ew2T : which == 2 ? cw1T : nw2T) + (size_t)l * HH * HH;
        for (int idx = threadIdx.x; idx < HH * HH; idx += blockDim.x) {
            const int k = idx >> 7, c = idx & 127;
            dst[c * HH + k] = f2bf(src[idx]);
        }
    }
}

// ---------------- per-layer: P = h@Wr + eb1, Q = h@Wc (bf16 MFMA) ----------------
// grid 512: (node-tile of 16) x (col half). Wave w: 32 cols.
__global__ __launch_bounds__(256) void pq_kernel(const float* __restrict__ h,
                                                 const short* __restrict__ ew1Tl,
                                                 const float* __restrict__ eb1l,
                                                 float* __restrict__ P, float* __restrict__ Q) {
    const int g0n = (blockIdx.x >> 1) * 16;
    const int half = blockIdx.x & 1;
    const int t = threadIdx.x;
    const int w = t >> 6, l = t & 63, l15 = l & 15, l4 = l >> 4;
    __shared__ __align__(16) char shN[16 * 256];  // [16 rows][128 bf16], swizzled

    {
        const int row = t >> 4, k0 = (t & 15) * 8;
        const float* hp = h + (size_t)(g0n + row) * HH + k0;
        const float4 a = *(const float4*)hp;
        const float4 b = *(const float4*)(hp + 4);
        const float av[8] = {a.x, a.y, a.z, a.w, b.x, b.y, b.z, b.w};
        bf16x8 s;
#pragma unroll
        for (int u = 0; u < 8; ++u) s[u] = f2bf(av[u]);
        *(bf16x8*)(shN + row * 256 + ((k0 * 2) ^ ((row & 7) << 4))) = s;
    }
    __syncthreads();

    const int c0 = half * 128 + w * 32;
    f32x4 acc[2];
    acc[0] = (f32x4){0.f, 0.f, 0.f, 0.f};
    acc[1] = (f32x4){0.f, 0.f, 0.f, 0.f};
#pragma unroll
    for (int kt = 0; kt < 4; ++kt) {
        const bf16x8 af = *(const bf16x8*)(shN + l15 * 256 + (((kt * 4 + l4) * 16) ^ ((l15 & 7) << 4)));
#pragma unroll
        for (int ct2 = 0; ct2 < 2; ++ct2) {
            const bf16x8 bf = *(const bf16x8*)(ew1Tl + (size_t)(c0 + ct2 * 16 + l15) * HH + kt * 32 + l4 * 8);
            acc[ct2] = __builtin_amdgcn_mfma_f32_16x16x32_bf16(af, bf, acc[ct2], 0, 0, 0);
        }
    }
#pragma unroll
    for (int ct2 = 0; ct2 < 2; ++ct2) {
        const int cp = c0 + ct2 * 16 + l15;
        const int c = cp & 127;
        float* dst = (cp >= HH) ? Q : P;
        const float bias = (cp >= HH) ? 0.0f : eb1l[c];
#pragma unroll
        for (int reg = 0; reg < 4; ++reg) {
            const int n = g0n + l4 * 4 + reg;
            dst[(size_t)n * HH + c] = acc[ct2][reg] + bias;
        }
    }
}

// ---------------- per-layer edge kernel: one block per row-node ----------------
__global__ __launch_bounds__(256) void edge_kernel(
    const float* __restrict__ P, const float* __restrict__ Q,
    const float* __restrict__ x, const float* __restrict__ x0,
    const float* __restrict__ em,
    const float* __restrict__ ew1l,   // [258][128] (rows 256,257 used)
    const short* __restrict__ ew2T,   // [128 cols][128 k] bf16
    const float* __restrict__ eb2l,
    const short* __restrict__ cw1T,   // [128 cols][128 k] bf16
    const float* __restrict__ cb1l,
    const float* __restrict__ cw2l,
    float* __restrict__ x_out, float* __restrict__ agg) {

    const int r = blockIdx.x;
    const int i = r & (NN - 1);
    const int g0 = r & ~(NN - 1);
    const int t = threadIdx.x;       // 256
    const int w = t >> 6;            // wave 0..3
    const int l = t & 63;
    const int l15 = l & 15, l4 = l >> 4;
    const int c0 = w * 32;           // wave's column base

    __shared__ __align__(16) char shAc[NN * 256];   // [64 rows][128 bf16], swizzled (16 KB)
    __shared__ float shP[HH], shw256[HH], shw257[HH];
    __shared__ float shEb2[HH], shCb1[HH], shCw2[HH];
    __shared__ float shx[NN * 3], shx0g[NN * 3];
    __shared__ float shrad[NN], shea[NN], shem[NN], shcdn[NN * 3];
    __shared__ float shphiP[4][NN];

    if (t < HH) {
        shP[t] = P[r * HH + t];
        shw256[t] = ew1l[256 * HH + t];
        shw257[t] = ew1l[257 * HH + t];
        shEb2[t] = eb2l[t];
        shCb1[t] = cb1l[t];
        shCw2[t] = cw2l[t];
    }
    if (t < NN * 3) {
        shx[t] = x[g0 * 3 + t];
        shx0g[t] = x0[g0 * 3 + t];
    }
    __syncthreads();
    if (t < NN) {
        const int j = t;
        float dx = shx[i * 3 + 0] - shx[j * 3 + 0];
        float dy = shx[i * 3 + 1] - shx[j * 3 + 1];
        float dz = shx[i * 3 + 2] - shx[j * 3 + 2];
        float rad = dx * dx + dy * dy + dz * dz;
        shrad[j] = rad;
        float inv = 1.0f / (sqrtf(rad + 1e-8f) + 1.0f);
        shcdn[j * 3 + 0] = dx * inv;
        shcdn[j * 3 + 1] = dy * inv;
        shcdn[j * 3 + 2] = dz * inv;
        float ex = shx0g[i * 3 + 0] - shx0g[j * 3 + 0];
        float ey = shx0g[i * 3 + 1] - shx0g[j * 3 + 1];
        float ez = shx0g[i * 3 + 2] - shx0g[j * 3 + 2];
        shea[j] = ex * ex + ey * ey + ez * ez;
        shem[j] = em[r * NN + j];
    }
    __syncthreads();

    // ---- build t1 rows: thread t builds row t>>2, k-chunks (t&3)*8 + p*32 ----
    {
        const int j = t >> 2;
        const float rad = shrad[j], ea = shea[j];
#pragma unroll
        for (int p = 0; p < 4; ++p) {
            const int k0 = (t & 3) * 8 + p * 32;
            const float4 qa = *(const float4*)(Q + (size_t)(g0 + j) * HH + k0);
            const float4 qb = *(const float4*)(Q + (size_t)(g0 + j) * HH + k0 + 4);
            const float qv[8] = {qa.x, qa.y, qa.z, qa.w, qb.x, qb.y, qb.z, qb.w};
            bf16x8 s;
#pragma unroll
            for (int u = 0; u < 8; ++u) {
                const int k = k0 + u;
                float v = shP[k] + qv[u] + rad * shw256[k] + ea * shw257[k];
                s[u] = f2bf(silu_f(v));
            }
            const int byte = j * 256 + ((k0 * 2) ^ ((j & 7) << 4));
            *(bf16x8*)(shAc + byte) = s;
        }
    }
    __syncthreads();  // cross-wave A reads below

    // ---- GEMM2: m = silu(t1 @ ew2 + eb2) * em  (col-sliced, B double-buffered) ----
    f32x4 acc[4][2];  // [row-tile][col-tile]
#pragma unroll
    for (int rt = 0; rt < 4; ++rt) {
        acc[rt][0] = (f32x4){0.f, 0.f, 0.f, 0.f};
        acc[rt][1] = (f32x4){0.f, 0.f, 0.f, 0.f};
    }
    {
        const short* B2 = ew2T + (size_t)(c0 + l15) * HH + l4 * 8;
        bf16x8 bcur[2], bnxt[2];
        bcur[0] = *(const bf16x8*)(B2);
        bcur[1] = *(const bf16x8*)(B2 + 16 * HH);
#pragma unroll
        for (int kt = 0; kt < 4; ++kt) {
            if (kt < 3) {
                bnxt[0] = *(const bf16x8*)(B2 + (kt + 1) * 32);
                bnxt[1] = *(const bf16x8*)(B2 + 16 * HH + (kt + 1) * 32);
            }
            bf16x8 af[4];
#pragma unroll
            for (int rt = 0; rt < 4; ++rt) {
                const int row = rt * 16 + l15;
                af[rt] = *(const bf16x8*)(shAc + row * 256 + (((kt * 4 + l4) * 16) ^ ((row & 7) << 4)));
            }
#pragma unroll
            for (int rt = 0; rt < 4; ++rt) {
                acc[rt][0] = __builtin_amdgcn_mfma_f32_16x16x32_bf16(af[rt], bcur[0], acc[rt][0], 0, 0, 0);
                acc[rt][1] = __builtin_amdgcn_mfma_f32_16x16x32_bf16(af[rt], bcur[1], acc[rt][1], 0, 0, 0);
            }
            bcur[0] = bnxt[0];
            bcur[1] = bnxt[1];
        }
    }
    __syncthreads();  // GEMM2 A-reads done before m overwrites shAc

    // epilogue: m = silu(acc+eb2)*em -> shAc (swizzled); agg fully in-wave
#pragma unroll
    for (int ct2 = 0; ct2 < 2; ++ct2) {
        const int c = c0 + ct2 * 16 + l15;
        const float b = shEb2[c];
        float pagg = 0.0f;
#pragma unroll
        for (int rt = 0; rt < 4; ++rt) {
#pragma unroll
            for (int reg = 0; reg < 4; ++reg) {
                const int row = rt * 16 + l4 * 4 + reg;
                float v = silu_f(acc[rt][ct2][reg] + b) * shem[row];
                pagg += v;
                const int byte = row * 256 + ((c * 2) ^ ((row & 7) << 4));
                *(short*)(shAc + byte) = f2bf(v);
            }
        }
        pagg += __shfl_xor(pagg, 16);
        pagg += __shfl_xor(pagg, 32);
        if (l4 == 0) agg[r * HH + c] = pagg;
    }
    __syncthreads();  // m complete before GEMM3 cross-wave A reads

    // ---- GEMM3: c1 = m @ cw1 ----
#pragma unroll
    for (int rt = 0; rt < 4; ++rt) {
        acc[rt][0] = (f32x4){0.f, 0.f, 0.f, 0.f};
        acc[rt][1] = (f32x4){0.f, 0.f, 0.f, 0.f};
    }
    {
        const short* B3 = cw1T + (size_t)(c0 + l15) * HH + l4 * 8;
        bf16x8 bcur[2], bnxt[2];
        bcur[0] = *(const bf16x8*)(B3);
        bcur[1] = *(const bf16x8*)(B3 + 16 * HH);
#pragma unroll
        for (int kt = 0; kt < 4; ++kt) {
            if (kt < 3) {
                bnxt[0] = *(const bf16x8*)(B3 + (kt + 1) * 32);
                bnxt[1] = *(const bf16x8*)(B3 + 16 * HH + (kt + 1) * 32);
            }
            bf16x8 af[4];
#pragma unroll
            for (int rt = 0; rt < 4; ++rt) {
                const int row = rt * 16 + l15;
                af[rt] = *(const bf16x8*)(shAc + row * 256 + (((kt * 4 + l4) * 16) ^ ((row & 7) << 4)));
            }
#pragma unroll
            for (int rt = 0; rt < 4; ++rt) {
                acc[rt][0] = __builtin_amdgcn_mfma_f32_16x16x32_bf16(af[rt], bcur[0], acc[rt][0], 0, 0, 0);
                acc[rt][1] = __builtin_amdgcn_mfma_f32_16x16x32_bf16(af[rt], bcur[1], acc[rt][1], 0, 0, 0);
            }
            bcur[0] = bnxt[0];
            bcur[1] = bnxt[1];
        }
    }

    // epilogue: phi partials (wave covers its 32 cols), reduce over l15
    {
        float pp[4][4];
#pragma unroll
        for (int rt = 0; rt < 4; ++rt)
#pragma unroll
            for (int reg = 0; reg < 4; ++reg) pp[rt][reg] = 0.0f;
#pragma unroll
        for (int ct2 = 0; ct2 < 2; ++ct2) {
            const int c = c0 + ct2 * 16 + l15;
            const float cb = shCb1[c], cw = shCw2[c];
#pragma unroll
            for (int rt = 0; rt < 4; ++rt) {
#pragma unroll
                for (int reg = 0; reg < 4; ++reg) {
                    float v = silu_f(acc[rt][ct2][reg] + cb);
                    pp[rt][reg] = fmaf(v, cw, pp[rt][reg]);
                }
            }
        }
#pragma unroll
        for (int off = 8; off >= 1; off >>= 1) {
#pragma unroll
            for (int rt = 0; rt < 4; ++rt)
#pragma unroll
                for (int reg = 0; reg < 4; ++reg) pp[rt][reg] += __shfl_xor(pp[rt][reg], off);
        }
        if (l15 == 0) {
#pragma unroll
            for (int rt = 0; rt < 4; ++rt)
#pragma unroll
                for (int reg = 0; reg < 4; ++reg)
                    shphiP[w][rt * 16 + l4 * 4 + reg] = pp[rt][reg];
        }
    }
    __syncthreads();

    // x_out[r] = x[r] + sum_j cdn[j]*phi[j]*em[j]  (3 waves, one per coord)
    if (t < 192) {
        const int q = t >> 6, j = t & 63;
        const float phi = shphiP[0][j] + shphiP[1][j] + shphiP[2][j] + shphiP[3][j];
        float v = shcdn[j * 3 + q] * phi * shem[j];
#pragma unroll
        for (int off = 32; off >= 1; off >>= 1) v += __shfl_xor(v, off);
        if (j == 0) x_out[r * 3 + q] = shx[i * 3 + q] + v;
    }
}

// ---------------- per-layer node update, bf16 MFMA (in place) ----------------
// grid 256: 16 nodes/block. Wave w: cols [w*32, w*32+32).
__global__ __launch_bounds__(256) void node_kernel(float* __restrict__ h, const float* __restrict__ agg,
                            const float* __restrict__ nm,
                            const short* __restrict__ nw1Tl, const float* __restrict__ nb1l,
                            const short* __restrict__ nw2Tl, const float* __restrict__ nb2l) {
    const int g0n = blockIdx.x * 16;
    const int t = threadIdx.x;
    const int w = t >> 6, l = t & 63, l15 = l & 15, l4 = l >> 4;
    __shared__ __align__(16) char shN[16 * 512];  // [16 rows][256 bf16] = [h|agg], swizzled
    __shared__ __align__(16) char shT[16 * 256];  // [16 rows][128 bf16], swizzled

    {
        const int row = t >> 4, k0 = (t & 15) * 16;
        const float* src = (k0 < HH) ? (h + (size_t)(g0n + row) * HH + k0)
                                     : (agg + (size_t)(g0n + row) * HH + (k0 - HH));
        const float4 a = *(const float4*)src;
        const float4 b = *(const float4*)(src + 4);
        const float4 c = *(const float4*)(src + 8);
        const float4 d = *(const float4*)(src + 12);
        const float av[16] = {a.x, a.y, a.z, a.w, b.x, b.y, b.z, b.w,
                              c.x, c.y, c.z, c.w, d.x, d.y, d.z, d.w};
        bf16x8 s0, s1;
#pragma unroll
        for (int u = 0; u < 8; ++u) { s0[u] = f2bf(av[u]); s1[u] = f2bf(av[8 + u]); }
        const int xr = (row & 7) << 4;
        *(bf16x8*)(shN + row * 512 + ((k0 * 2) ^ xr)) = s0;
        *(bf16x8*)(shN + row * 512 + ((k0 * 2 + 16) ^ xr)) = s1;
    }
    __syncthreads();

    const int c0 = w * 32;
    f32x4 acc[2];
    acc[0] = (f32x4){0.f, 0.f, 0.f, 0.f};
    acc[1] = (f32x4){0.f, 0.f, 0.f, 0.f};
#pragma unroll
    for (int kt = 0; kt < 8; ++kt) {
        const bf16x8 af = *(const bf16x8*)(shN + l15 * 512 + (((kt * 4 + l4) * 16) ^ ((l15 & 7) << 4)));
#pragma unroll
        for (int ct2 = 0; ct2 < 2; ++ct2) {
            const bf16x8 bf = *(const bf16x8*)(nw1Tl + (size_t)(c0 + ct2 * 16 + l15) * 256 + kt * 32 + l4 * 8);
            acc[ct2] = __builtin_amdgcn_mfma_f32_16x16x32_bf16(af, bf, acc[ct2], 0, 0, 0);
        }
    }
#pragma unroll
    for (int ct2 = 0; ct2 < 2; ++ct2) {
        const int c = c0 + ct2 * 16 + l15;
        const float b = nb1l[c];
#pragma unroll
        for (int reg = 0; reg < 4; ++reg) {
            const int row = l4 * 4 + reg;
            const float v = silu_f(acc[ct2][reg] + b);
            *(short*)(shT + row * 256 + ((c * 2) ^ ((row & 7) << 4))) = f2bf(v);
        }
    }
    __syncthreads();

    acc[0] = (f32x4){0.f, 0.f, 0.f, 0.f};
    acc[1] = (f32x4){0.f, 0.f, 0.f, 0.f};
#pragma unroll
    for (int kt = 0; kt < 4; ++kt) {
        const bf16x8 af = *(const bf16x8*)(shT + l15 * 256 + (((kt * 4 + l4) * 16) ^ ((l15 & 7) << 4)));
#pragma unroll
        for (int ct2 = 0; ct2 < 2; ++ct2) {
            const bf16x8 bf = *(const bf16x8*)(nw2Tl + (size_t)(c0 + ct2 * 16 + l15) * HH + kt * 32 + l4 * 8);
            acc[ct2] = __builtin_amdgcn_mfma_f32_16x16x32_bf16(af, bf, acc[ct2], 0, 0, 0);
        }
    }
#pragma unroll
    for (int ct2 = 0; ct2 < 2; ++ct2) {
        const int c = c0 + ct2 * 16 + l15;
        const float b = nb2l[c];
#pragma unroll
        for (int reg = 0; reg < 4; ++reg) {
            const int n = g0n + l4 * 4 + reg;
            const float hv = h[(size_t)n * HH + c];
            h[(size_t)n * HH + c] = (hv + acc[ct2][reg] + b) * nm[n];
        }
    }
}

// ---------------- output: per-graph mean of (h@out_w + out_b)*nm ----------------
__global__ void out_kernel(const float* __restrict__ h, const float* __restrict__ nm,
                           const float* __restrict__ ow, const float* __restrict__ ob,
                           float* __restrict__ out) {
    const int b = blockIdx.x;
    const int n = threadIdx.x;  // 64
    const int v = b * NN + n;
    float acc = 0.0f;
#pragma unroll 8
    for (int c = 0; c < HH; ++c) acc = fmaf(h[v * HH + c], ow[c], acc);
    acc = (acc + ob[0]) * nm[v];
#pragma unroll
    for (int off = 32; off >= 1; off >>= 1) acc += __shfl_xor(acc, off);
    if (n == 0) out[b] = acc * (1.0f / (float)NN);
}

extern "C" void kernel_launch(void* const* d_in, const int* in_sizes, int n_in,
                              void* d_out, int out_size, void* d_ws, size_t ws_size,
                              hipStream_t stream) {
    const float* xh    = (const float*)d_in[0];
    const float* nmask = (const float*)d_in[1];
    const float* emask = (const float*)d_in[2];
    const float* emb_w = (const float*)d_in[3];
    const float* emb_b = (const float*)d_in[4];
    const float* out_w = (const float*)d_in[5];
    const float* out_b = (const float*)d_in[6];
    const float* ew1   = (const float*)d_in[7];
    const float* eb1   = (const float*)d_in[8];
    const float* ew2   = (const float*)d_in[9];
    const float* eb2   = (const float*)d_in[10];
    const float* nw1   = (const float*)d_in[11];
    const float* nb1   = (const float*)d_in[12];
    const float* nw2   = (const float*)d_in[13];
    const float* nb2   = (const float*)d_in[14];
    const float* cw1   = (const float*)d_in[15];
    const float* cb1   = (const float*)d_in[16];
    const float* cw2   = (const float*)d_in[17];

    float* ws  = (float*)d_ws;
    float* xA  = ws;                    // [4096*3]
    float* xB  = xA + BNODES * 3;       // [4096*3]
    float* x0  = xB + BNODES * 3;       // [4096*3]
    float* h   = x0 + BNODES * 3;       // [4096*128]
    float* Pb  = h + BNODES * HH;       // [4096*128]
    float* Qb  = Pb + BNODES * HH;      // [4096*128]
    float* agg = Qb + BNODES * HH;      // [4096*128]
    short* ew2T = (short*)(agg + BNODES * HH);  // [4][128*128] bf16
    short* cw1T = ew2T + LL * HH * HH;          // [4][128*128] bf16
    short* ew1T = cw1T + LL * HH * HH;          // [4][256*128] bf16
    short* nw1T = ew1T + LL * 256 * HH;         // [4][128*256] bf16
    short* nw2T = nw1T + LL * 256 * HH;         // [4][128*128] bf16

    prep_kernel<<<BNODES, HH, 0, stream>>>(xh, nmask, emb_w, emb_b, xA, x0, h);
    wprep_kernel<<<5 * LL, 256, 0, stream>>>(ew1, ew2, cw1, nw1, nw2,
                                             ew1T, ew2T, cw1T, nw1T, nw2T);

    float* xc = xA;
    float* xn = xB;
    for (int l = 0; l < LL; ++l) {
        const float* ew1l = ew1 + (size_t)l * 258 * HH;
        pq_kernel<<<512, 256, 0, stream>>>(h, ew1T + (size_t)l * 256 * HH, eb1 + l * HH, Pb, Qb);
        edge_kernel<<<BNODES, 256, 0, stream>>>(Pb, Qb, xc, x0, emask, ew1l,
                                                ew2T + (size_t)l * HH * HH, eb2 + l * HH,
                                                cw1T + (size_t)l * HH * HH, cb1 + l * HH,
                                                cw2 + (size_t)l * HH, xn, agg);
        node_kernel<<<256, 256, 0, stream>>>(h, agg, nmask,
                                             nw1T + (size_t)l * 2 * HH * HH, nb1 + l * HH,
                                             nw2T + (size_t)l * HH * HH, nb2 + l * HH);
        float* tmp = xc; xc = xn; xn = tmp;
    }

    out_kernel<<<NB, NN, 0, stream>>>(h, nmask, out_w, out_b, (float*)d_out);
}

// Round 6
// 341.453 us; speedup vs baseline: 3.7238x; 1.0322x over previous
//
#include <hip/hip_runtime.h>
#include <math.h>

// EGNN: B=64 graphs x N=64 nodes, D=3, IN_NF=8, H=128, L=4 layers.
// e_in @ ew1 = P[row] + Q[col] + radial*w256 + ea*w257 (per-node GEMMs).
// R6: edge kernel processes TWO row-nodes (iA, iA+32) of the same graph per
// block (grid 2048): Q loads, B weight loads, staging and barriers amortized
// 2x. f2bf reverted to manual RNE (native __bf16 cast cost VGPRs + time).

#define NB 64
#define NN 64
#define DD 3
#define INNF 8
#define HH 128
#define LL 4
#define BNODES (NB * NN)  // 4096

typedef __attribute__((ext_vector_type(8))) short bf16x8;
typedef __attribute__((ext_vector_type(4))) float f32x4;

__device__ __forceinline__ float silu_f(float v) {
    float e = __expf(-v);
    return v * __builtin_amdgcn_rcpf(1.0f + e);
}

__device__ __forceinline__ short f2bf(float v) {
    unsigned u = __builtin_bit_cast(unsigned, v);
    u += 0x7fffu + ((u >> 16) & 1u);  // RNE (finite values only)
    return (short)(u >> 16);
}

// ---------------- prep: x, x0, h = (feat*nm)@emb_w + emb_b ----------------
__global__ void prep_kernel(const float* __restrict__ xh, const float* __restrict__ nm,
                            const float* __restrict__ emb_w, const float* __restrict__ emb_b,
                            float* __restrict__ x, float* __restrict__ x0, float* __restrict__ h) {
    const int v = blockIdx.x;
    const int t = threadIdx.x;  // 128
    const float m = nm[v];
    __shared__ float f[INNF];
    if (t < INNF) f[t] = xh[v * (DD + INNF) + DD + t] * m;
    if (t < DD) {
        float c = xh[v * (DD + INNF) + t] * m;
        x[v * DD + t] = c;
        x0[v * DD + t] = c;
    }
    __syncthreads();
    float acc = emb_b[t];
#pragma unroll
    for (int k = 0; k < INNF; ++k) acc = fmaf(f[k], emb_w[k * HH + t], acc);
    h[v * HH + t] = acc;
}

// ---------------- weight prep: bf16, K-contiguous per output column ----------------
__global__ void wprep_kernel(const float* __restrict__ ew1, const float* __restrict__ ew2,
                             const float* __restrict__ cw1, const float* __restrict__ nw1,
                             const float* __restrict__ nw2,
                             short* __restrict__ ew1T, short* __restrict__ ew2T,
                             short* __restrict__ cw1T, short* __restrict__ nw1T,
                             short* __restrict__ nw2T) {
    const int l = blockIdx.x / 5, which = blockIdx.x % 5;
    if (which == 0) {
        const float* src = ew1 + (size_t)l * 258 * HH;
        short* dst = ew1T + (size_t)l * 256 * HH;
        for (int idx = threadIdx.x; idx < 256 * HH; idx += blockDim.x) {
            const int cp = idx >> 7, k = idx & 127;
            dst[cp * HH + k] = f2bf(src[(k + ((cp >> 7) << 7)) * HH + (cp & 127)]);
        }
    } else if (which == 3) {
        const float* src = nw1 + (size_t)l * 2 * HH * HH;
        short* dst = nw1T + (size_t)l * 2 * HH * HH;
        for (int idx = threadIdx.x; idx < 2 * HH * HH; idx += blockDim.x) {
            const int c = idx >> 8, k = idx & 255;
            dst[c * 256 + k] = f2bf(src[k * HH + c]);
        }
    } else {
        const float* src = (which == 1 ? ew2 : which == 2 ? cw1 : nw2) + (size_t)l * HH * HH;
        short* dst = (which == 1 ? ew2T : which == 2 ? cw1T : nw2T) + (size_t)l * HH * HH;
        for (int idx = threadIdx.x; idx < HH * HH; idx += blockDim.x) {
            const int k = idx >> 7, c = idx & 127;
            dst[c * HH + k] = f2bf(src[idx]);
        }
    }
}

// ---------------- per-layer: P = h@Wr + eb1, Q = h@Wc (bf16 MFMA) ----------------
__global__ __launch_bounds__(256) void pq_kernel(const float* __restrict__ h,
                                                 const short* __restrict__ ew1Tl,
                                                 const float* __restrict__ eb1l,
                                                 float* __restrict__ P, float* __restrict__ Q) {
    const int g0n = (blockIdx.x >> 1) * 16;
    const int half = blockIdx.x & 1;
    const int t = threadIdx.x;
    const int w = t >> 6, l = t & 63, l15 = l & 15, l4 = l >> 4;
    __shared__ __align__(16) char shN[16 * 256];

    {
        const int row = t >> 4, k0 = (t & 15) * 8;
        const float* hp = h + (size_t)(g0n + row) * HH + k0;
        const float4 a = *(const float4*)hp;
        const float4 b = *(const float4*)(hp + 4);
        const float av[8] = {a.x, a.y, a.z, a.w, b.x, b.y, b.z, b.w};
        bf16x8 s;
#pragma unroll
        for (int u = 0; u < 8; ++u) s[u] = f2bf(av[u]);
        *(bf16x8*)(shN + row * 256 + ((k0 * 2) ^ ((row & 7) << 4))) = s;
    }
    __syncthreads();

    const int c0 = half * 128 + w * 32;
    f32x4 acc[2];
    acc[0] = (f32x4){0.f, 0.f, 0.f, 0.f};
    acc[1] = (f32x4){0.f, 0.f, 0.f, 0.f};
#pragma unroll
    for (int kt = 0; kt < 4; ++kt) {
        const bf16x8 af = *(const bf16x8*)(shN + l15 * 256 + (((kt * 4 + l4) * 16) ^ ((l15 & 7) << 4)));
#pragma unroll
        for (int ct2 = 0; ct2 < 2; ++ct2) {
            const bf16x8 bf = *(const bf16x8*)(ew1Tl + (size_t)(c0 + ct2 * 16 + l15) * HH + kt * 32 + l4 * 8);
            acc[ct2] = __builtin_amdgcn_mfma_f32_16x16x32_bf16(af, bf, acc[ct2], 0, 0, 0);
        }
    }
#pragma unroll
    for (int ct2 = 0; ct2 < 2; ++ct2) {
        const int cp = c0 + ct2 * 16 + l15;
        const int c = cp & 127;
        float* dst = (cp >= HH) ? Q : P;
        const float bias = (cp >= HH) ? 0.0f : eb1l[c];
#pragma unroll
        for (int reg = 0; reg < 4; ++reg) {
            const int n = g0n + l4 * 4 + reg;
            dst[(size_t)n * HH + c] = acc[ct2][reg] + bias;
        }
    }
}

// ---------------- per-layer edge kernel: TWO row-nodes per block ----------------
__global__ __launch_bounds__(256) void edge_kernel(
    const float* __restrict__ P, const float* __restrict__ Q,
    const float* __restrict__ x, const float* __restrict__ x0,
    const float* __restrict__ em,
    const float* __restrict__ ew1l,   // [258][128] (rows 256,257 used)
    const short* __restrict__ ew2T,   // [128 cols][128 k] bf16
    const float* __restrict__ eb2l,
    const short* __restrict__ cw1T,   // [128 cols][128 k] bf16
    const float* __restrict__ cb1l,
    const float* __restrict__ cw2l,
    float* __restrict__ x_out, float* __restrict__ agg) {

    const int g  = blockIdx.x >> 5;
    const int ii = blockIdx.x & 31;
    const int iA = ii, iB = ii + 32;
    const int g0 = g * NN;
    const int rA = g0 + iA, rB = g0 + iB;
    const int t = threadIdx.x;       // 256
    const int w = t >> 6;
    const int l = t & 63;
    const int l15 = l & 15, l4 = l >> 4;
    const int c0 = w * 32;

    __shared__ __align__(16) char shAc[128 * 256];  // rows 0-63: node A, 64-127: node B (32 KB)
    __shared__ float shPA[HH], shPB[HH], shw256[HH], shw257[HH];
    __shared__ float shEb2[HH], shCb1[HH], shCw2[HH];
    __shared__ float shx[NN * 3], shx0g[NN * 3];
    __shared__ float shradA[NN], shradB[NN], sheaA[NN], sheaB[NN], shemA[NN], shemB[NN];
    __shared__ float shcdnA[NN * 3], shcdnB[NN * 3];
    __shared__ float shphiP[4][128];

    if (t < HH) {
        shPA[t] = P[rA * HH + t];
        shPB[t] = P[rB * HH + t];
        shw256[t] = ew1l[256 * HH + t];
        shw257[t] = ew1l[257 * HH + t];
        shEb2[t] = eb2l[t];
        shCb1[t] = cb1l[t];
        shCw2[t] = cw2l[t];
    }
    if (t < NN * 3) {
        shx[t] = x[g0 * 3 + t];
        shx0g[t] = x0[g0 * 3 + t];
    }
    __syncthreads();
    if (t < 2 * NN) {  // wave0: node A geometry, wave1: node B (wave-uniform)
        const int j = t & 63;
        const bool isB = (t >= NN);
        const int ni = isB ? iB : iA;
        float dx = shx[ni * 3 + 0] - shx[j * 3 + 0];
        float dy = shx[ni * 3 + 1] - shx[j * 3 + 1];
        float dz = shx[ni * 3 + 2] - shx[j * 3 + 2];
        float rad = dx * dx + dy * dy + dz * dz;
        float inv = 1.0f / (sqrtf(rad + 1e-8f) + 1.0f);
        float ex = shx0g[ni * 3 + 0] - shx0g[j * 3 + 0];
        float ey = shx0g[ni * 3 + 1] - shx0g[j * 3 + 1];
        float ez = shx0g[ni * 3 + 2] - shx0g[j * 3 + 2];
        float ea = ex * ex + ey * ey + ez * ez;
        float* radp = isB ? shradB : shradA;
        float* eap  = isB ? sheaB : sheaA;
        float* emp  = isB ? shemB : shemA;
        float* cdnp = isB ? shcdnB : shcdnA;
        radp[j] = rad;
        eap[j] = ea;
        emp[j] = em[(isB ? rB : rA) * NN + j];
        cdnp[j * 3 + 0] = dx * inv;
        cdnp[j * 3 + 1] = dy * inv;
        cdnp[j * 3 + 2] = dz * inv;
    }
    __syncthreads();

    // ---- build t1 rows for BOTH nodes (Q row loaded once, used twice) ----
    {
        const int j = t >> 2;  // 0..63
        const float radA = shradA[j], eaA = sheaA[j];
        const float radB = shradB[j], eaB = sheaB[j];
        const int xr = (j & 7) << 4;
#pragma unroll
        for (int p = 0; p < 4; ++p) {
            const int k0 = (t & 3) * 32 + p * 8;  // slot spread: conflict-2-way (free)
            const float4 qa = *(const float4*)(Q + (size_t)(g0 + j) * HH + k0);
            const float4 qb = *(const float4*)(Q + (size_t)(g0 + j) * HH + k0 + 4);
            const float qv[8] = {qa.x, qa.y, qa.z, qa.w, qb.x, qb.y, qb.z, qb.w};
            bf16x8 sA, sB;
#pragma unroll
            for (int u = 0; u < 8; ++u) {
                const int k = k0 + u;
                const float w2 = shw256[k], w3 = shw257[k];
                float vA = shPA[k] + qv[u] + radA * w2 + eaA * w3;
                float vB = shPB[k] + qv[u] + radB * w2 + eaB * w3;
                sA[u] = f2bf(silu_f(vA));
                sB[u] = f2bf(silu_f(vB));
            }
            const int off = (k0 * 2) ^ xr;
            *(bf16x8*)(shAc + j * 256 + off) = sA;
            *(bf16x8*)(shAc + (j + 64) * 256 + off) = sB;  // (j+64)&7 == j&7
        }
    }
    __syncthreads();

    // ---- GEMM2: m = silu(t1 @ ew2 + eb2) * em  (col-sliced, B double-buffered) ----
    f32x4 acc[8][2];
#pragma unroll
    for (int rt = 0; rt < 8; ++rt) {
        acc[rt][0] = (f32x4){0.f, 0.f, 0.f, 0.f};
        acc[rt][1] = (f32x4){0.f, 0.f, 0.f, 0.f};
    }
    {
        const short* B2 = ew2T + (size_t)(c0 + l15) * HH + l4 * 8;
        bf16x8 bcur[2], bnxt[2];
        bcur[0] = *(const bf16x8*)(B2);
        bcur[1] = *(const bf16x8*)(B2 + 16 * HH);
#pragma unroll
        for (int kt = 0; kt < 4; ++kt) {
            if (kt < 3) {
                bnxt[0] = *(const bf16x8*)(B2 + (kt + 1) * 32);
                bnxt[1] = *(const bf16x8*)(B2 + 16 * HH + (kt + 1) * 32);
            }
            bf16x8 af[8];
#pragma unroll
            for (int rt = 0; rt < 8; ++rt) {
                const int row = rt * 16 + l15;
                af[rt] = *(const bf16x8*)(shAc + row * 256 + (((kt * 4 + l4) * 16) ^ ((row & 7) << 4)));
            }
#pragma unroll
            for (int rt = 0; rt < 8; ++rt) {
                acc[rt][0] = __builtin_amdgcn_mfma_f32_16x16x32_bf16(af[rt], bcur[0], acc[rt][0], 0, 0, 0);
                acc[rt][1] = __builtin_amdgcn_mfma_f32_16x16x32_bf16(af[rt], bcur[1], acc[rt][1], 0, 0, 0);
            }
            bcur[0] = bnxt[0];
            bcur[1] = bnxt[1];
        }
    }
    __syncthreads();  // GEMM2 A-reads done before m overwrites shAc

    // epilogue: m = silu(acc+eb2)*em -> shAc; agg in-wave for both nodes
#pragma unroll
    for (int ct2 = 0; ct2 < 2; ++ct2) {
        const int c = c0 + ct2 * 16 + l15;
        const float b = shEb2[c];
        float paggA = 0.0f, paggB = 0.0f;
#pragma unroll
        for (int rt = 0; rt < 8; ++rt) {
#pragma unroll
            for (int reg = 0; reg < 4; ++reg) {
                const int row = rt * 16 + l4 * 4 + reg;
                const float emv = (rt < 4) ? shemA[row] : shemB[row - 64];
                float v = silu_f(acc[rt][ct2][reg] + b) * emv;
                if (rt < 4) paggA += v; else paggB += v;
                const int byte = row * 256 + ((c * 2) ^ ((row & 7) << 4));
                *(short*)(shAc + byte) = f2bf(v);
            }
        }
        paggA += __shfl_xor(paggA, 16);
        paggA += __shfl_xor(paggA, 32);
        paggB += __shfl_xor(paggB, 16);
        paggB += __shfl_xor(paggB, 32);
        if (l4 == 0) {
            agg[rA * HH + c] = paggA;
            agg[rB * HH + c] = paggB;
        }
    }
    __syncthreads();  // m complete before GEMM3 A reads

    // ---- GEMM3: c1 = m @ cw1 ----
#pragma unroll
    for (int rt = 0; rt < 8; ++rt) {
        acc[rt][0] = (f32x4){0.f, 0.f, 0.f, 0.f};
        acc[rt][1] = (f32x4){0.f, 0.f, 0.f, 0.f};
    }
    {
        const short* B3 = cw1T + (size_t)(c0 + l15) * HH + l4 * 8;
        bf16x8 bcur[2], bnxt[2];
        bcur[0] = *(const bf16x8*)(B3);
        bcur[1] = *(const bf16x8*)(B3 + 16 * HH);
#pragma unroll
        for (int kt = 0; kt < 4; ++kt) {
            if (kt < 3) {
                bnxt[0] = *(const bf16x8*)(B3 + (kt + 1) * 32);
                bnxt[1] = *(const bf16x8*)(B3 + 16 * HH + (kt + 1) * 32);
            }
            bf16x8 af[8];
#pragma unroll
            for (int rt = 0; rt < 8; ++rt) {
                const int row = rt * 16 + l15;
                af[rt] = *(const bf16x8*)(shAc + row * 256 + (((kt * 4 + l4) * 16) ^ ((row & 7) << 4)));
            }
#pragma unroll
            for (int rt = 0; rt < 8; ++rt) {
                acc[rt][0] = __builtin_amdgcn_mfma_f32_16x16x32_bf16(af[rt], bcur[0], acc[rt][0], 0, 0, 0);
                acc[rt][1] = __builtin_amdgcn_mfma_f32_16x16x32_bf16(af[rt], bcur[1], acc[rt][1], 0, 0, 0);
            }
            bcur[0] = bnxt[0];
            bcur[1] = bnxt[1];
        }
    }

    // epilogue: phi partials, reduce over l15 within wave, stash per-wave
    {
        float pp[8][4];
#pragma unroll
        for (int rt = 0; rt < 8; ++rt)
#pragma unroll
            for (int reg = 0; reg < 4; ++reg) pp[rt][reg] = 0.0f;
#pragma unroll
        for (int ct2 = 0; ct2 < 2; ++ct2) {
            const int c = c0 + ct2 * 16 + l15;
            const float cb = shCb1[c], cw = shCw2[c];
#pragma unroll
            for (int rt = 0; rt < 8; ++rt) {
#pragma unroll
                for (int reg = 0; reg < 4; ++reg) {
                    float v = silu_f(acc[rt][ct2][reg] + cb);
                    pp[rt][reg] = fmaf(v, cw, pp[rt][reg]);
                }
            }
        }
#pragma unroll
        for (int off = 8; off >= 1; off >>= 1) {
#pragma unroll
            for (int rt = 0; rt < 8; ++rt)
#pragma unroll
                for (int reg = 0; reg < 4; ++reg) pp[rt][reg] += __shfl_xor(pp[rt][reg], off);
        }
        if (l15 == 0) {
#pragma unroll
            for (int rt = 0; rt < 8; ++rt)
#pragma unroll
                for (int reg = 0; reg < 4; ++reg)
                    shphiP[w][rt * 16 + l4 * 4 + reg] = pp[rt][reg];
        }
    }
    __syncthreads();

    // x_out for both nodes (3 waves, one per coord; two sequential reductions)
    if (t < 192) {
        const int q = t >> 6, j = t & 63;
        float phiA = shphiP[0][j] + shphiP[1][j] + shphiP[2][j] + shphiP[3][j];
        float vA = shcdnA[j * 3 + q] * phiA * shemA[j];
        float phiB = shphiP[0][64 + j] + shphiP[1][64 + j] + shphiP[2][64 + j] + shphiP[3][64 + j];
        float vB = shcdnB[j * 3 + q] * phiB * shemB[j];
#pragma unroll
        for (int off = 32; off >= 1; off >>= 1) {
            vA += __shfl_xor(vA, off);
            vB += __shfl_xor(vB, off);
        }
        if (j == 0) {
            x_out[rA * 3 + q] = shx[iA * 3 + q] + vA;
            x_out[rB * 3 + q] = shx[iB * 3 + q] + vB;
        }
    }
}

// ---------------- per-layer node update, bf16 MFMA (in place) ----------------
__global__ __launch_bounds__(256) void node_kernel(float* __restrict__ h, const float* __restrict__ agg,
                            const float* __restrict__ nm,
                            const short* __restrict__ nw1Tl, const float* __restrict__ nb1l,
                            const short* __restrict__ nw2Tl, const float* __restrict__ nb2l) {
    const int g0n = blockIdx.x * 16;
    const int t = threadIdx.x;
    const int w = t >> 6, l = t & 63, l15 = l & 15, l4 = l >> 4;
    __shared__ __align__(16) char shN[16 * 512];
    __shared__ __align__(16) char shT[16 * 256];

    {
        const int row = t >> 4, k0 = (t & 15) * 16;
        const float* src = (k0 < HH) ? (h + (size_t)(g0n + row) * HH + k0)
                                     : (agg + (size_t)(g0n + row) * HH + (k0 - HH));
        const float4 a = *(const float4*)src;
        const float4 b = *(const float4*)(src + 4);
        const float4 c = *(const float4*)(src + 8);
        const float4 d = *(const float4*)(src + 12);
        const float av[16] = {a.x, a.y, a.z, a.w, b.x, b.y, b.z, b.w,
                              c.x, c.y, c.z, c.w, d.x, d.y, d.z, d.w};
        bf16x8 s0, s1;
#pragma unroll
        for (int u = 0; u < 8; ++u) { s0[u] = f2bf(av[u]); s1[u] = f2bf(av[8 + u]); }
        const int xr = (row & 7) << 4;
        *(bf16x8*)(shN + row * 512 + ((k0 * 2) ^ xr)) = s0;
        *(bf16x8*)(shN + row * 512 + ((k0 * 2 + 16) ^ xr)) = s1;
    }
    __syncthreads();

    const int c0 = w * 32;
    f32x4 acc[2];
    acc[0] = (f32x4){0.f, 0.f, 0.f, 0.f};
    acc[1] = (f32x4){0.f, 0.f, 0.f, 0.f};
#pragma unroll
    for (int kt = 0; kt < 8; ++kt) {
        const bf16x8 af = *(const bf16x8*)(shN + l15 * 512 + (((kt * 4 + l4) * 16) ^ ((l15 & 7) << 4)));
#pragma unroll
        for (int ct2 = 0; ct2 < 2; ++ct2) {
            const bf16x8 bf = *(const bf16x8*)(nw1Tl + (size_t)(c0 + ct2 * 16 + l15) * 256 + kt * 32 + l4 * 8);
            acc[ct2] = __builtin_amdgcn_mfma_f32_16x16x32_bf16(af, bf, acc[ct2], 0, 0, 0);
        }
    }
#pragma unroll
    for (int ct2 = 0; ct2 < 2; ++ct2) {
        const int c = c0 + ct2 * 16 + l15;
        const float b = nb1l[c];
#pragma unroll
        for (int reg = 0; reg < 4; ++reg) {
            const int row = l4 * 4 + reg;
            const float v = silu_f(acc[ct2][reg] + b);
            *(short*)(shT + row * 256 + ((c * 2) ^ ((row & 7) << 4))) = f2bf(v);
        }
    }
    __syncthreads();

    acc[0] = (f32x4){0.f, 0.f, 0.f, 0.f};
    acc[1] = (f32x4){0.f, 0.f, 0.f, 0.f};
#pragma unroll
    for (int kt = 0; kt < 4; ++kt) {
        const bf16x8 af = *(const bf16x8*)(shT + l15 * 256 + (((kt * 4 + l4) * 16) ^ ((l15 & 7) << 4)));
#pragma unroll
        for (int ct2 = 0; ct2 < 2; ++ct2) {
            const bf16x8 bf = *(const bf16x8*)(nw2Tl + (size_t)(c0 + ct2 * 16 + l15) * HH + kt * 32 + l4 * 8);
            acc[ct2] = __builtin_amdgcn_mfma_f32_16x16x32_bf16(af, bf, acc[ct2], 0, 0, 0);
        }
    }
#pragma unroll
    for (int ct2 = 0; ct2 < 2; ++ct2) {
        const int c = c0 + ct2 * 16 + l15;
        const float b = nb2l[c];
#pragma unroll
        for (int reg = 0; reg < 4; ++reg) {
            const int n = g0n + l4 * 4 + reg;
            const float hv = h[(size_t)n * HH + c];
            h[(size_t)n * HH + c] = (hv + acc[ct2][reg] + b) * nm[n];
        }
    }
}

// ---------------- output: per-graph mean of (h@out_w + out_b)*nm ----------------
__global__ void out_kernel(const float* __restrict__ h, const float* __restrict__ nm,
                           const float* __restrict__ ow, const float* __restrict__ ob,
                           float* __restrict__ out) {
    const int b = blockIdx.x;
    const int n = threadIdx.x;  // 64
    const int v = b * NN + n;
    float acc = 0.0f;
#pragma unroll 8
    for (int c = 0; c < HH; ++c) acc = fmaf(h[v * HH + c], ow[c], acc);
    acc = (acc + ob[0]) * nm[v];
#pragma unroll
    for (int off = 32; off >= 1; off >>= 1) acc += __shfl_xor(acc, off);
    if (n == 0) out[b] = acc * (1.0f / (float)NN);
}

extern "C" void kernel_launch(void* const* d_in, const int* in_sizes, int n_in,
                              void* d_out, int out_size, void* d_ws, size_t ws_size,
                              hipStream_t stream) {
    const float* xh    = (const float*)d_in[0];
    const float* nmask = (const float*)d_in[1];
    const float* emask = (const float*)d_in[2];
    const float* emb_w = (const float*)d_in[3];
    const float* emb_b = (const float*)d_in[4];
    const float* out_w = (const float*)d_in[5];
    const float* out_b = (const float*)d_in[6];
    const float* ew1   = (const float*)d_in[7];
    const float* eb1   = (const float*)d_in[8];
    const float* ew2   = (const float*)d_in[9];
    const float* eb2   = (const float*)d_in[10];
    const float* nw1   = (const float*)d_in[11];
    const float* nb1   = (const float*)d_in[12];
    const float* nw2   = (const float*)d_in[13];
    const float* nb2   = (const float*)d_in[14];
    const float* cw1   = (const float*)d_in[15];
    const float* cb1   = (const float*)d_in[16];
    const float* cw2   = (const float*)d_in[17];

    float* ws  = (float*)d_ws;
    float* xA  = ws;                    // [4096*3]
    float* xB  = xA + BNODES * 3;       // [4096*3]
    float* x0  = xB + BNODES * 3;       // [4096*3]
    float* h   = x0 + BNODES * 3;       // [4096*128]
    float* Pb  = h + BNODES * HH;       // [4096*128]
    float* Qb  = Pb + BNODES * HH;      // [4096*128]
    float* agg = Qb + BNODES * HH;      // [4096*128]
    short* ew2T = (short*)(agg + BNODES * HH);  // [4][128*128] bf16
    short* cw1T = ew2T + LL * HH * HH;          // [4][128*128] bf16
    short* ew1T = cw1T + LL * HH * HH;          // [4][256*128] bf16
    short* nw1T = ew1T + LL * 256 * HH;         // [4][128*256] bf16
    short* nw2T = nw1T + LL * 256 * HH;         // [4][128*128] bf16

    prep_kernel<<<BNODES, HH, 0, stream>>>(xh, nmask, emb_w, emb_b, xA, x0, h);
    wprep_kernel<<<5 * LL, 256, 0, stream>>>(ew1, ew2, cw1, nw1, nw2,
                                             ew1T, ew2T, cw1T, nw1T, nw2T);

    float* xc = xA;
    float* xn = xB;
    for (int l = 0; l < LL; ++l) {
        const float* ew1l = ew1 + (size_t)l * 258 * HH;
        pq_kernel<<<512, 256, 0, stream>>>(h, ew1T + (size_t)l * 256 * HH, eb1 + l * HH, Pb, Qb);
        edge_kernel<<<BNODES / 2, 256, 0, stream>>>(Pb, Qb, xc, x0, emask, ew1l,
                                                    ew2T + (size_t)l * HH * HH, eb2 + l * HH,
                                                    cw1T + (size_t)l * HH * HH, cb1 + l * HH,
                                                    cw2 + (size_t)l * HH, xn, agg);
        node_kernel<<<256, 256, 0, stream>>>(h, agg, nmask,
                                             nw1T + (size_t)l * 2 * HH * HH, nb1 + l * HH,
                                             nw2T + (size_t)l * HH * HH, nb2 + l * HH);
        float* tmp = xc; xc = xn; xn = tmp;
    }

    out_kernel<<<NB, NN, 0, stream>>>(h, nmask, out_w, out_b, (float*)d_out);
}

// Round 7
// 296.520 us; speedup vs baseline: 4.2881x; 1.1515x over previous
//
#include <hip/hip_runtime.h>
#include <math.h>

// EGNN: B=64 graphs x N=64 nodes, D=3, IN_NF=8, H=128, L=4 layers.
// e_in @ ew1 = P[row] + Q[col] + radial*w256 + ea*w257 (per-node GEMMs).
// R7: LDS overlay (shphiP + shx0g carved from shAc's dead phases) ->
// 40192 B -> 4 blocks/CU (was 3); launch_bounds(256,4); build k-map
// reverted to R5 pattern (lower measured conflicts).

#define NB 64
#define NN 64
#define DD 3
#define INNF 8
#define HH 128
#define LL 4
#define BNODES (NB * NN)  // 4096

typedef __attribute__((ext_vector_type(8))) short bf16x8;
typedef __attribute__((ext_vector_type(4))) float f32x4;

__device__ __forceinline__ float silu_f(float v) {
    float e = __expf(-v);
    return v * __builtin_amdgcn_rcpf(1.0f + e);
}

__device__ __forceinline__ short f2bf(float v) {
    unsigned u = __builtin_bit_cast(unsigned, v);
    u += 0x7fffu + ((u >> 16) & 1u);  // RNE (finite values only)
    return (short)(u >> 16);
}

// ---------------- prep: x, x0, h = (feat*nm)@emb_w + emb_b ----------------
__global__ void prep_kernel(const float* __restrict__ xh, const float* __restrict__ nm,
                            const float* __restrict__ emb_w, const float* __restrict__ emb_b,
                            float* __restrict__ x, float* __restrict__ x0, float* __restrict__ h) {
    const int v = blockIdx.x;
    const int t = threadIdx.x;  // 128
    const float m = nm[v];
    __shared__ float f[INNF];
    if (t < INNF) f[t] = xh[v * (DD + INNF) + DD + t] * m;
    if (t < DD) {
        float c = xh[v * (DD + INNF) + t] * m;
        x[v * DD + t] = c;
        x0[v * DD + t] = c;
    }
    __syncthreads();
    float acc = emb_b[t];
#pragma unroll
    for (int k = 0; k < INNF; ++k) acc = fmaf(f[k], emb_w[k * HH + t], acc);
    h[v * HH + t] = acc;
}

// ---------------- weight prep: bf16, K-contiguous per output column ----------------
__global__ void wprep_kernel(const float* __restrict__ ew1, const float* __restrict__ ew2,
                             const float* __restrict__ cw1, const float* __restrict__ nw1,
                             const float* __restrict__ nw2,
                             short* __restrict__ ew1T, short* __restrict__ ew2T,
                             short* __restrict__ cw1T, short* __restrict__ nw1T,
                             short* __restrict__ nw2T) {
    const int l = blockIdx.x / 5, which = blockIdx.x % 5;
    if (which == 0) {
        const float* src = ew1 + (size_t)l * 258 * HH;
        short* dst = ew1T + (size_t)l * 256 * HH;
        for (int idx = threadIdx.x; idx < 256 * HH; idx += blockDim.x) {
            const int cp = idx >> 7, k = idx & 127;
            dst[cp * HH + k] = f2bf(src[(k + ((cp >> 7) << 7)) * HH + (cp & 127)]);
        }
    } else if (which == 3) {
        const float* src = nw1 + (size_t)l * 2 * HH * HH;
        short* dst = nw1T + (size_t)l * 2 * HH * HH;
        for (int idx = threadIdx.x; idx < 2 * HH * HH; idx += blockDim.x) {
            const int c = idx >> 8, k = idx & 255;
            dst[c * 256 + k] = f2bf(src[k * HH + c]);
        }
    } else {
        const float* src = (which == 1 ? ew2 : which == 2 ? cw1 : nw2) + (size_t)l * HH * HH;
        short* dst = (which == 1 ? ew2T : which == 2 ? cw1T : nw2T) + (size_t)l * HH * HH;
        for (int idx = threadIdx.x; idx < HH * HH; idx += blockDim.x) {
            const int k = idx >> 7, c = idx & 127;
            dst[c * HH + k] = f2bf(src[idx]);
        }
    }
}

// ---------------- per-layer: P = h@Wr + eb1, Q = h@Wc (bf16 MFMA) ----------------
__global__ __launch_bounds__(256) void pq_kernel(const float* __restrict__ h,
                                                 const short* __restrict__ ew1Tl,
                                                 const float* __restrict__ eb1l,
                                                 float* __restrict__ P, float* __restrict__ Q) {
    const int g0n = (blockIdx.x >> 1) * 16;
    const int half = blockIdx.x & 1;
    const int t = threadIdx.x;
    const int w = t >> 6, l = t & 63, l15 = l & 15, l4 = l >> 4;
    __shared__ __align__(16) char shN[16 * 256];

    {
        const int row = t >> 4, k0 = (t & 15) * 8;
        const float* hp = h + (size_t)(g0n + row) * HH + k0;
        const float4 a = *(const float4*)hp;
        const float4 b = *(const float4*)(hp + 4);
        const float av[8] = {a.x, a.y, a.z, a.w, b.x, b.y, b.z, b.w};
        bf16x8 s;
#pragma unroll
        for (int u = 0; u < 8; ++u) s[u] = f2bf(av[u]);
        *(bf16x8*)(shN + row * 256 + ((k0 * 2) ^ ((row & 7) << 4))) = s;
    }
    __syncthreads();

    const int c0 = half * 128 + w * 32;
    f32x4 acc[2];
    acc[0] = (f32x4){0.f, 0.f, 0.f, 0.f};
    acc[1] = (f32x4){0.f, 0.f, 0.f, 0.f};
#pragma unroll
    for (int kt = 0; kt < 4; ++kt) {
        const bf16x8 af = *(const bf16x8*)(shN + l15 * 256 + (((kt * 4 + l4) * 16) ^ ((l15 & 7) << 4)));
#pragma unroll
        for (int ct2 = 0; ct2 < 2; ++ct2) {
            const bf16x8 bf = *(const bf16x8*)(ew1Tl + (size_t)(c0 + ct2 * 16 + l15) * HH + kt * 32 + l4 * 8);
            acc[ct2] = __builtin_amdgcn_mfma_f32_16x16x32_bf16(af, bf, acc[ct2], 0, 0, 0);
        }
    }
#pragma unroll
    for (int ct2 = 0; ct2 < 2; ++ct2) {
        const int cp = c0 + ct2 * 16 + l15;
        const int c = cp & 127;
        float* dst = (cp >= HH) ? Q : P;
        const float bias = (cp >= HH) ? 0.0f : eb1l[c];
#pragma unroll
        for (int reg = 0; reg < 4; ++reg) {
            const int n = g0n + l4 * 4 + reg;
            dst[(size_t)n * HH + c] = acc[ct2][reg] + bias;
        }
    }
}

// ---------------- per-layer edge kernel: TWO row-nodes per block ----------------
__global__ __launch_bounds__(256, 4) void edge_kernel(
    const float* __restrict__ P, const float* __restrict__ Q,
    const float* __restrict__ x, const float* __restrict__ x0,
    const float* __restrict__ em,
    const float* __restrict__ ew1l,   // [258][128] (rows 256,257 used)
    const short* __restrict__ ew2T,   // [128 cols][128 k] bf16
    const float* __restrict__ eb2l,
    const short* __restrict__ cw1T,   // [128 cols][128 k] bf16
    const float* __restrict__ cb1l,
    const float* __restrict__ cw2l,
    float* __restrict__ x_out, float* __restrict__ agg) {

    const int g  = blockIdx.x >> 5;
    const int ii = blockIdx.x & 31;
    const int iA = ii, iB = ii + 32;
    const int g0 = g * NN;
    const int rA = g0 + iA, rB = g0 + iB;
    const int t = threadIdx.x;       // 256
    const int w = t >> 6;
    const int l = t & 63;
    const int l15 = l & 15, l4 = l >> 4;
    const int c0 = w * 32;

    __shared__ __align__(16) char shAc[128 * 256];  // rows 0-63: node A, 64-127: node B (32 KB)
    // phase-disjoint overlays inside shAc:
    //   shphiP (4*128 f32, 2048 B @ off 0)  - used only AFTER GEMM3 reads
    //   shx0g  (192 f32,    768 B @ off 2048) - used only BEFORE build writes
    float* shphiP = (float*)(shAc);
    float* shx0g  = (float*)(shAc + 2048);
    __shared__ float shPA[HH], shPB[HH], shw256[HH], shw257[HH];
    __shared__ float shEb2[HH], shCb1[HH], shCw2[HH];
    __shared__ float shx[NN * 3];
    __shared__ float shradA[NN], shradB[NN], sheaA[NN], sheaB[NN], shemA[NN], shemB[NN];
    __shared__ float shcdnA[NN * 3], shcdnB[NN * 3];

    if (t < HH) {
        shPA[t] = P[rA * HH + t];
        shPB[t] = P[rB * HH + t];
        shw256[t] = ew1l[256 * HH + t];
        shw257[t] = ew1l[257 * HH + t];
        shEb2[t] = eb2l[t];
        shCb1[t] = cb1l[t];
        shCw2[t] = cw2l[t];
    }
    if (t < NN * 3) {
        shx[t] = x[g0 * 3 + t];
        shx0g[t] = x0[g0 * 3 + t];
    }
    __syncthreads();
    if (t < 2 * NN) {  // wave0: node A geometry, wave1: node B (wave-uniform)
        const int j = t & 63;
        const bool isB = (t >= NN);
        const int ni = isB ? iB : iA;
        float dx = shx[ni * 3 + 0] - shx[j * 3 + 0];
        float dy = shx[ni * 3 + 1] - shx[j * 3 + 1];
        float dz = shx[ni * 3 + 2] - shx[j * 3 + 2];
        float rad = dx * dx + dy * dy + dz * dz;
        float inv = 1.0f / (sqrtf(rad + 1e-8f) + 1.0f);
        float ex = shx0g[ni * 3 + 0] - shx0g[j * 3 + 0];
        float ey = shx0g[ni * 3 + 1] - shx0g[j * 3 + 1];
        float ez = shx0g[ni * 3 + 2] - shx0g[j * 3 + 2];
        float ea = ex * ex + ey * ey + ez * ez;
        float* radp = isB ? shradB : shradA;
        float* eap  = isB ? sheaB : sheaA;
        float* emp  = isB ? shemB : shemA;
        float* cdnp = isB ? shcdnB : shcdnA;
        radp[j] = rad;
        eap[j] = ea;
        emp[j] = em[(isB ? rB : rA) * NN + j];
        cdnp[j * 3 + 0] = dx * inv;
        cdnp[j * 3 + 1] = dy * inv;
        cdnp[j * 3 + 2] = dz * inv;
    }
    __syncthreads();  // geometry done; shx0g overlay now dead

    // ---- build t1 rows for BOTH nodes (Q row loaded once, used twice) ----
    {
        const int j = t >> 2;  // 0..63
        const float radA = shradA[j], eaA = sheaA[j];
        const float radB = shradB[j], eaB = sheaB[j];
        const int xr = (j & 7) << 4;
#pragma unroll
        for (int p = 0; p < 4; ++p) {
            const int k0 = (t & 3) * 8 + p * 32;  // R5 mapping (lower measured conflicts)
            const float4 qa = *(const float4*)(Q + (size_t)(g0 + j) * HH + k0);
            const float4 qb = *(const float4*)(Q + (size_t)(g0 + j) * HH + k0 + 4);
            const float qv[8] = {qa.x, qa.y, qa.z, qa.w, qb.x, qb.y, qb.z, qb.w};
            bf16x8 sA, sB;
#pragma unroll
            for (int u = 0; u < 8; ++u) {
                const int k = k0 + u;
                const float w2 = shw256[k], w3 = shw257[k];
                float vA = shPA[k] + qv[u] + radA * w2 + eaA * w3;
                float vB = shPB[k] + qv[u] + radB * w2 + eaB * w3;
                sA[u] = f2bf(silu_f(vA));
                sB[u] = f2bf(silu_f(vB));
            }
            const int off = (k0 * 2) ^ xr;
            *(bf16x8*)(shAc + j * 256 + off) = sA;
            *(bf16x8*)(shAc + (j + 64) * 256 + off) = sB;  // (j+64)&7 == j&7
        }
    }
    __syncthreads();

    // ---- GEMM2: m = silu(t1 @ ew2 + eb2) * em  (col-sliced, B double-buffered) ----
    f32x4 acc[8][2];
#pragma unroll
    for (int rt = 0; rt < 8; ++rt) {
        acc[rt][0] = (f32x4){0.f, 0.f, 0.f, 0.f};
        acc[rt][1] = (f32x4){0.f, 0.f, 0.f, 0.f};
    }
    {
        const short* B2 = ew2T + (size_t)(c0 + l15) * HH + l4 * 8;
        bf16x8 bcur[2], bnxt[2];
        bcur[0] = *(const bf16x8*)(B2);
        bcur[1] = *(const bf16x8*)(B2 + 16 * HH);
#pragma unroll
        for (int kt = 0; kt < 4; ++kt) {
            if (kt < 3) {
                bnxt[0] = *(const bf16x8*)(B2 + (kt + 1) * 32);
                bnxt[1] = *(const bf16x8*)(B2 + 16 * HH + (kt + 1) * 32);
            }
            bf16x8 af[8];
#pragma unroll
            for (int rt = 0; rt < 8; ++rt) {
                const int row = rt * 16 + l15;
                af[rt] = *(const bf16x8*)(shAc + row * 256 + (((kt * 4 + l4) * 16) ^ ((row & 7) << 4)));
            }
#pragma unroll
            for (int rt = 0; rt < 8; ++rt) {
                acc[rt][0] = __builtin_amdgcn_mfma_f32_16x16x32_bf16(af[rt], bcur[0], acc[rt][0], 0, 0, 0);
                acc[rt][1] = __builtin_amdgcn_mfma_f32_16x16x32_bf16(af[rt], bcur[1], acc[rt][1], 0, 0, 0);
            }
            bcur[0] = bnxt[0];
            bcur[1] = bnxt[1];
        }
    }
    __syncthreads();  // GEMM2 A-reads done before m overwrites shAc

    // epilogue: m = silu(acc+eb2)*em -> shAc; agg in-wave for both nodes
#pragma unroll
    for (int ct2 = 0; ct2 < 2; ++ct2) {
        const int c = c0 + ct2 * 16 + l15;
        const float b = shEb2[c];
        float paggA = 0.0f, paggB = 0.0f;
#pragma unroll
        for (int rt = 0; rt < 8; ++rt) {
#pragma unroll
            for (int reg = 0; reg < 4; ++reg) {
                const int row = rt * 16 + l4 * 4 + reg;
                const float emv = (rt < 4) ? shemA[row] : shemB[row - 64];
                float v = silu_f(acc[rt][ct2][reg] + b) * emv;
                if (rt < 4) paggA += v; else paggB += v;
                const int byte = row * 256 + ((c * 2) ^ ((row & 7) << 4));
                *(short*)(shAc + byte) = f2bf(v);
            }
        }
        paggA += __shfl_xor(paggA, 16);
        paggA += __shfl_xor(paggA, 32);
        paggB += __shfl_xor(paggB, 16);
        paggB += __shfl_xor(paggB, 32);
        if (l4 == 0) {
            agg[rA * HH + c] = paggA;
            agg[rB * HH + c] = paggB;
        }
    }
    __syncthreads();  // m complete before GEMM3 A reads

    // ---- GEMM3: c1 = m @ cw1 ----
#pragma unroll
    for (int rt = 0; rt < 8; ++rt) {
        acc[rt][0] = (f32x4){0.f, 0.f, 0.f, 0.f};
        acc[rt][1] = (f32x4){0.f, 0.f, 0.f, 0.f};
    }
    {
        const short* B3 = cw1T + (size_t)(c0 + l15) * HH + l4 * 8;
        bf16x8 bcur[2], bnxt[2];
        bcur[0] = *(const bf16x8*)(B3);
        bcur[1] = *(const bf16x8*)(B3 + 16 * HH);
#pragma unroll
        for (int kt = 0; kt < 4; ++kt) {
            if (kt < 3) {
                bnxt[0] = *(const bf16x8*)(B3 + (kt + 1) * 32);
                bnxt[1] = *(const bf16x8*)(B3 + 16 * HH + (kt + 1) * 32);
            }
            bf16x8 af[8];
#pragma unroll
            for (int rt = 0; rt < 8; ++rt) {
                const int row = rt * 16 + l15;
                af[rt] = *(const bf16x8*)(shAc + row * 256 + (((kt * 4 + l4) * 16) ^ ((row & 7) << 4)));
            }
#pragma unroll
            for (int rt = 0; rt < 8; ++rt) {
                acc[rt][0] = __builtin_amdgcn_mfma_f32_16x16x32_bf16(af[rt], bcur[0], acc[rt][0], 0, 0, 0);
                acc[rt][1] = __builtin_amdgcn_mfma_f32_16x16x32_bf16(af[rt], bcur[1], acc[rt][1], 0, 0, 0);
            }
            bcur[0] = bnxt[0];
            bcur[1] = bnxt[1];
        }
    }

    // epilogue: phi partials, reduce over l15 within wave
    float pp[8][4];
    {
#pragma unroll
        for (int rt = 0; rt < 8; ++rt)
#pragma unroll
            for (int reg = 0; reg < 4; ++reg) pp[rt][reg] = 0.0f;
#pragma unroll
        for (int ct2 = 0; ct2 < 2; ++ct2) {
            const int c = c0 + ct2 * 16 + l15;
            const float cb = shCb1[c], cw = shCw2[c];
#pragma unroll
            for (int rt = 0; rt < 8; ++rt) {
#pragma unroll
                for (int reg = 0; reg < 4; ++reg) {
                    float v = silu_f(acc[rt][ct2][reg] + cb);
                    pp[rt][reg] = fmaf(v, cw, pp[rt][reg]);
                }
            }
        }
#pragma unroll
        for (int off = 8; off >= 1; off >>= 1) {
#pragma unroll
            for (int rt = 0; rt < 8; ++rt)
#pragma unroll
                for (int reg = 0; reg < 4; ++reg) pp[rt][reg] += __shfl_xor(pp[rt][reg], off);
        }
    }
    __syncthreads();  // ALL GEMM3 shAc reads done -> shphiP overlay safe
    if (l15 == 0) {
#pragma unroll
        for (int rt = 0; rt < 8; ++rt)
#pragma unroll
            for (int reg = 0; reg < 4; ++reg)
                shphiP[w * 128 + rt * 16 + l4 * 4 + reg] = pp[rt][reg];
    }
    __syncthreads();

    // x_out for both nodes (3 waves, one per coord; two sequential reductions)
    if (t < 192) {
        const int q = t >> 6, j = t & 63;
        float phiA = shphiP[0 * 128 + j] + shphiP[1 * 128 + j] + shphiP[2 * 128 + j] + shphiP[3 * 128 + j];
        float vA = shcdnA[j * 3 + q] * phiA * shemA[j];
        float phiB = shphiP[0 * 128 + 64 + j] + shphiP[1 * 128 + 64 + j] + shphiP[2 * 128 + 64 + j] + shphiP[3 * 128 + 64 + j];
        float vB = shcdnB[j * 3 + q] * phiB * shemB[j];
#pragma unroll
        for (int off = 32; off >= 1; off >>= 1) {
            vA += __shfl_xor(vA, off);
            vB += __shfl_xor(vB, off);
        }
        if (j == 0) {
            x_out[rA * 3 + q] = shx[iA * 3 + q] + vA;
            x_out[rB * 3 + q] = shx[iB * 3 + q] + vB;
        }
    }
}

// ---------------- per-layer node update, bf16 MFMA (in place) ----------------
__global__ __launch_bounds__(256) void node_kernel(float* __restrict__ h, const float* __restrict__ agg,
                            const float* __restrict__ nm,
                            const short* __restrict__ nw1Tl, const float* __restrict__ nb1l,
                            const short* __restrict__ nw2Tl, const float* __restrict__ nb2l) {
    const int g0n = blockIdx.x * 16;
    const int t = threadIdx.x;
    const int w = t >> 6, l = t & 63, l15 = l & 15, l4 = l >> 4;
    __shared__ __align__(16) char shN[16 * 512];
    __shared__ __align__(16) char shT[16 * 256];

    {
        const int row = t >> 4, k0 = (t & 15) * 16;
        const float* src = (k0 < HH) ? (h + (size_t)(g0n + row) * HH + k0)
                                     : (agg + (size_t)(g0n + row) * HH + (k0 - HH));
        const float4 a = *(const float4*)src;
        const float4 b = *(const float4*)(src + 4);
        const float4 c = *(const float4*)(src + 8);
        const float4 d = *(const float4*)(src + 12);
        const float av[16] = {a.x, a.y, a.z, a.w, b.x, b.y, b.z, b.w,
                              c.x, c.y, c.z, c.w, d.x, d.y, d.z, d.w};
        bf16x8 s0, s1;
#pragma unroll
        for (int u = 0; u < 8; ++u) { s0[u] = f2bf(av[u]); s1[u] = f2bf(av[8 + u]); }
        const int xr = (row & 7) << 4;
        *(bf16x8*)(shN + row * 512 + ((k0 * 2) ^ xr)) = s0;
        *(bf16x8*)(shN + row * 512 + ((k0 * 2 + 16) ^ xr)) = s1;
    }
    __syncthreads();

    const int c0 = w * 32;
    f32x4 acc[2];
    acc[0] = (f32x4){0.f, 0.f, 0.f, 0.f};
    acc[1] = (f32x4){0.f, 0.f, 0.f, 0.f};
#pragma unroll
    for (int kt = 0; kt < 8; ++kt) {
        const bf16x8 af = *(const bf16x8*)(shN + l15 * 512 + (((kt * 4 + l4) * 16) ^ ((l15 & 7) << 4)));
#pragma unroll
        for (int ct2 = 0; ct2 < 2; ++ct2) {
            const bf16x8 bf = *(const bf16x8*)(nw1Tl + (size_t)(c0 + ct2 * 16 + l15) * 256 + kt * 32 + l4 * 8);
            acc[ct2] = __builtin_amdgcn_mfma_f32_16x16x32_bf16(af, bf, acc[ct2], 0, 0, 0);
        }
    }
#pragma unroll
    for (int ct2 = 0; ct2 < 2; ++ct2) {
        const int c = c0 + ct2 * 16 + l15;
        const float b = nb1l[c];
#pragma unroll
        for (int reg = 0; reg < 4; ++reg) {
            const int row = l4 * 4 + reg;
            const float v = silu_f(acc[ct2][reg] + b);
            *(short*)(shT + row * 256 + ((c * 2) ^ ((row & 7) << 4))) = f2bf(v);
        }
    }
    __syncthreads();

    acc[0] = (f32x4){0.f, 0.f, 0.f, 0.f};
    acc[1] = (f32x4){0.f, 0.f, 0.f, 0.f};
#pragma unroll
    for (int kt = 0; kt < 4; ++kt) {
        const bf16x8 af = *(const bf16x8*)(shT + l15 * 256 + (((kt * 4 + l4) * 16) ^ ((l15 & 7) << 4)));
#pragma unroll
        for (int ct2 = 0; ct2 < 2; ++ct2) {
            const bf16x8 bf = *(const bf16x8*)(nw2Tl + (size_t)(c0 + ct2 * 16 + l15) * HH + kt * 32 + l4 * 8);
            acc[ct2] = __builtin_amdgcn_mfma_f32_16x16x32_bf16(af, bf, acc[ct2], 0, 0, 0);
        }
    }
#pragma unroll
    for (int ct2 = 0; ct2 < 2; ++ct2) {
        const int c = c0 + ct2 * 16 + l15;
        const float b = nb2l[c];
#pragma unroll
        for (int reg = 0; reg < 4; ++reg) {
            const int n = g0n + l4 * 4 + reg;
            const float hv = h[(size_t)n * HH + c];
            h[(size_t)n * HH + c] = (hv + acc[ct2][reg] + b) * nm[n];
        }
    }
}

// ---------------- output: per-graph mean of (h@out_w + out_b)*nm ----------------
__global__ void out_kernel(const float* __restrict__ h, const float* __restrict__ nm,
                           const float* __restrict__ ow, const float* __restrict__ ob,
                           float* __restrict__ out) {
    const int b = blockIdx.x;
    const int n = threadIdx.x;  // 64
    const int v = b * NN + n;
    float acc = 0.0f;
#pragma unroll 8
    for (int c = 0; c < HH; ++c) acc = fmaf(h[v * HH + c], ow[c], acc);
    acc = (acc + ob[0]) * nm[v];
#pragma unroll
    for (int off = 32; off >= 1; off >>= 1) acc += __shfl_xor(acc, off);
    if (n == 0) out[b] = acc * (1.0f / (float)NN);
}

extern "C" void kernel_launch(void* const* d_in, const int* in_sizes, int n_in,
                              void* d_out, int out_size, void* d_ws, size_t ws_size,
                              hipStream_t stream) {
    const float* xh    = (const float*)d_in[0];
    const float* nmask = (const float*)d_in[1];
    const float* emask = (const float*)d_in[2];
    const float* emb_w = (const float*)d_in[3];
    const float* emb_b = (const float*)d_in[4];
    const float* out_w = (const float*)d_in[5];
    const float* out_b = (const float*)d_in[6];
    const float* ew1   = (const float*)d_in[7];
    const float* eb1   = (const float*)d_in[8];
    const float* ew2   = (const float*)d_in[9];
    const float* eb2   = (const float*)d_in[10];
    const float* nw1   = (const float*)d_in[11];
    const float* nb1   = (const float*)d_in[12];
    const float* nw2   = (const float*)d_in[13];
    const float* nb2   = (const float*)d_in[14];
    const float* cw1   = (const float*)d_in[15];
    const float* cb1   = (const float*)d_in[16];
    const float* cw2   = (const float*)d_in[17];

    float* ws  = (float*)d_ws;
    float* xA  = ws;                    // [4096*3]
    float* xB  = xA + BNODES * 3;       // [4096*3]
    float* x0  = xB + BNODES * 3;       // [4096*3]
    float* h   = x0 + BNODES * 3;       // [4096*128]
    float* Pb  = h + BNODES * HH;       // [4096*128]
    float* Qb  = Pb + BNODES * HH;      // [4096*128]
    float* agg = Qb + BNODES * HH;      // [4096*128]
    short* ew2T = (short*)(agg + BNODES * HH);  // [4][128*128] bf16
    short* cw1T = ew2T + LL * HH * HH;          // [4][128*128] bf16
    short* ew1T = cw1T + LL * HH * HH;          // [4][256*128] bf16
    short* nw1T = ew1T + LL * 256 * HH;         // [4][128*256] bf16
    short* nw2T = nw1T + LL * 256 * HH;         // [4][128*128] bf16

    prep_kernel<<<BNODES, HH, 0, stream>>>(xh, nmask, emb_w, emb_b, xA, x0, h);
    wprep_kernel<<<5 * LL, 256, 0, stream>>>(ew1, ew2, cw1, nw1, nw2,
                                             ew1T, ew2T, cw1T, nw1T, nw2T);

    float* xc = xA;
    float* xn = xB;
    for (int l = 0; l < LL; ++l) {
        const float* ew1l = ew1 + (size_t)l * 258 * HH;
        pq_kernel<<<512, 256, 0, stream>>>(h, ew1T + (size_t)l * 256 * HH, eb1 + l * HH, Pb, Qb);
        edge_kernel<<<BNODES / 2, 256, 0, stream>>>(Pb, Qb, xc, x0, emask, ew1l,
                                                    ew2T + (size_t)l * HH * HH, eb2 + l * HH,
                                                    cw1T + (size_t)l * HH * HH, cb1 + l * HH,
                                                    cw2 + (size_t)l * HH, xn, agg);
        node_kernel<<<256, 256, 0, stream>>>(h, agg, nmask,
                                             nw1T + (size_t)l * 2 * HH * HH, nb1 + l * HH,
                                             nw2T + (size_t)l * HH * HH, nb2 + l * HH);
        float* tmp = xc; xc = xn; xn = tmp;
    }

    out_kernel<<<NB, NN, 0, stream>>>(h, nmask, out_w, out_b, (float*)d_out);
}

// Round 8
// 284.538 us; speedup vs baseline: 4.4687x; 1.0421x over previous
//
#include <hip/hip_runtime.h>
#include <math.h>

// EGNN: B=64 graphs x N=64 nodes, D=3, IN_NF=8, H=128, L=4 layers.
// R8: v_cvt_pk_bf16_f32 packing (1 op / 2 values, was ~4 ops/value) in edge
// build + m-epilogue + staging paths; node_kernel fused with next layer's
// pq_kernel (h' regs -> LDS -> pq GEMM in-block; 3 fewer dispatches).

#define NB 64
#define NN 64
#define DD 3
#define INNF 8
#define HH 128
#define LL 4
#define BNODES (NB * NN)  // 4096

typedef __attribute__((ext_vector_type(8))) short bf16x8;
typedef __attribute__((ext_vector_type(4))) float f32x4;
typedef __attribute__((ext_vector_type(4))) unsigned uint32x4;

__device__ __forceinline__ float silu_f(float v) {
    float e = __expf(-v);
    return v * __builtin_amdgcn_rcpf(1.0f + e);
}

__device__ __forceinline__ short f2bf(float v) {
    unsigned u = __builtin_bit_cast(unsigned, v);
    u += 0x7fffu + ((u >> 16) & 1u);  // RNE (finite values only)
    return (short)(u >> 16);
}

// HW packed convert: lo -> bits[15:0], hi -> bits[31:16], RNE.
__device__ __forceinline__ unsigned cvt_pk2(float lo, float hi) {
    unsigned r;
    asm("v_cvt_pk_bf16_f32 %0, %1, %2" : "=v"(r) : "v"(lo), "v"(hi));
    return r;
}

// ---------------- prep: x, x0, h = (feat*nm)@emb_w + emb_b ----------------
__global__ void prep_kernel(const float* __restrict__ xh, const float* __restrict__ nm,
                            const float* __restrict__ emb_w, const float* __restrict__ emb_b,
                            float* __restrict__ x, float* __restrict__ x0, float* __restrict__ h) {
    const int v = blockIdx.x;
    const int t = threadIdx.x;  // 128
    const float m = nm[v];
    __shared__ float f[INNF];
    if (t < INNF) f[t] = xh[v * (DD + INNF) + DD + t] * m;
    if (t < DD) {
        float c = xh[v * (DD + INNF) + t] * m;
        x[v * DD + t] = c;
        x0[v * DD + t] = c;
    }
    __syncthreads();
    float acc = emb_b[t];
#pragma unroll
    for (int k = 0; k < INNF; ++k) acc = fmaf(f[k], emb_w[k * HH + t], acc);
    h[v * HH + t] = acc;
}

// ---------------- weight prep: bf16, K-contiguous per output column ----------------
__global__ void wprep_kernel(const float* __restrict__ ew1, const float* __restrict__ ew2,
                             const float* __restrict__ cw1, const float* __restrict__ nw1,
                             const float* __restrict__ nw2,
                             short* __restrict__ ew1T, short* __restrict__ ew2T,
                             short* __restrict__ cw1T, short* __restrict__ nw1T,
                             short* __restrict__ nw2T) {
    const int l = blockIdx.x / 5, which = blockIdx.x % 5;
    if (which == 0) {
        const float* src = ew1 + (size_t)l * 258 * HH;
        short* dst = ew1T + (size_t)l * 256 * HH;
        for (int idx = threadIdx.x; idx < 256 * HH; idx += blockDim.x) {
            const int cp = idx >> 7, k = idx & 127;
            dst[cp * HH + k] = f2bf(src[(k + ((cp >> 7) << 7)) * HH + (cp & 127)]);
        }
    } else if (which == 3) {
        const float* src = nw1 + (size_t)l * 2 * HH * HH;
        short* dst = nw1T + (size_t)l * 2 * HH * HH;
        for (int idx = threadIdx.x; idx < 2 * HH * HH; idx += blockDim.x) {
            const int c = idx >> 8, k = idx & 255;
            dst[c * 256 + k] = f2bf(src[k * HH + c]);
        }
    } else {
        const float* src = (which == 1 ? ew2 : which == 2 ? cw1 : nw2) + (size_t)l * HH * HH;
        short* dst = (which == 1 ? ew2T : which == 2 ? cw1T : nw2T) + (size_t)l * HH * HH;
        for (int idx = threadIdx.x; idx < HH * HH; idx += blockDim.x) {
            const int k = idx >> 7, c = idx & 127;
            dst[c * HH + k] = f2bf(src[idx]);
        }
    }
}

// ---------------- layer-0 pq: P = h@Wr + eb1, Q = h@Wc (bf16 MFMA) ----------------
__global__ __launch_bounds__(256) void pq_kernel(const float* __restrict__ h,
                                                 const short* __restrict__ ew1Tl,
                                                 const float* __restrict__ eb1l,
                                                 float* __restrict__ P, float* __restrict__ Q) {
    const int g0n = (blockIdx.x >> 1) * 16;
    const int half = blockIdx.x & 1;
    const int t = threadIdx.x;
    const int w = t >> 6, l = t & 63, l15 = l & 15, l4 = l >> 4;
    __shared__ __align__(16) char shN[16 * 256];

    {
        const int row = t >> 4, k0 = (t & 15) * 8;
        const float* hp = h + (size_t)(g0n + row) * HH + k0;
        const float4 a = *(const float4*)hp;
        const float4 b = *(const float4*)(hp + 4);
        uint32x4 s;
        s[0] = cvt_pk2(a.x, a.y);
        s[1] = cvt_pk2(a.z, a.w);
        s[2] = cvt_pk2(b.x, b.y);
        s[3] = cvt_pk2(b.z, b.w);
        *(uint32x4*)(shN + row * 256 + ((k0 * 2) ^ ((row & 7) << 4))) = s;
    }
    __syncthreads();

    const int c0 = half * 128 + w * 32;
    f32x4 acc[2];
    acc[0] = (f32x4){0.f, 0.f, 0.f, 0.f};
    acc[1] = (f32x4){0.f, 0.f, 0.f, 0.f};
#pragma unroll
    for (int kt = 0; kt < 4; ++kt) {
        const bf16x8 af = *(const bf16x8*)(shN + l15 * 256 + (((kt * 4 + l4) * 16) ^ ((l15 & 7) << 4)));
#pragma unroll
        for (int ct2 = 0; ct2 < 2; ++ct2) {
            const bf16x8 bf = *(const bf16x8*)(ew1Tl + (size_t)(c0 + ct2 * 16 + l15) * HH + kt * 32 + l4 * 8);
            acc[ct2] = __builtin_amdgcn_mfma_f32_16x16x32_bf16(af, bf, acc[ct2], 0, 0, 0);
        }
    }
#pragma unroll
    for (int ct2 = 0; ct2 < 2; ++ct2) {
        const int cp = c0 + ct2 * 16 + l15;
        const int c = cp & 127;
        float* dst = (cp >= HH) ? Q : P;
        const float bias = (cp >= HH) ? 0.0f : eb1l[c];
#pragma unroll
        for (int reg = 0; reg < 4; ++reg) {
            const int n = g0n + l4 * 4 + reg;
            dst[(size_t)n * HH + c] = acc[ct2][reg] + bias;
        }
    }
}

// ---------------- per-layer edge kernel: TWO row-nodes per block ----------------
__global__ __launch_bounds__(256, 4) void edge_kernel(
    const float* __restrict__ P, const float* __restrict__ Q,
    const float* __restrict__ x, const float* __restrict__ x0,
    const float* __restrict__ em,
    const float* __restrict__ ew1l,   // [258][128] (rows 256,257 used)
    const short* __restrict__ ew2T,   // [128 cols][128 k] bf16
    const float* __restrict__ eb2l,
    const short* __restrict__ cw1T,   // [128 cols][128 k] bf16
    const float* __restrict__ cb1l,
    const float* __restrict__ cw2l,
    float* __restrict__ x_out, float* __restrict__ agg) {

    const int g  = blockIdx.x >> 5;
    const int ii = blockIdx.x & 31;
    const int iA = ii, iB = ii + 32;
    const int g0 = g * NN;
    const int rA = g0 + iA, rB = g0 + iB;
    const int t = threadIdx.x;       // 256
    const int w = t >> 6;
    const int l = t & 63;
    const int l15 = l & 15, l4 = l >> 4;
    const int c0 = w * 32;

    __shared__ __align__(16) char shAc[128 * 256];  // rows 0-63: node A, 64-127: node B (32 KB)
    float* shphiP = (float*)(shAc);        // overlay: used only AFTER GEMM3 reads
    float* shx0g  = (float*)(shAc + 2048); // overlay: used only BEFORE build writes
    __shared__ float shPA[HH], shPB[HH], shw256[HH], shw257[HH];
    __shared__ float shEb2[HH], shCb1[HH], shCw2[HH];
    __shared__ float shx[NN * 3];
    __shared__ float shradA[NN], shradB[NN], sheaA[NN], sheaB[NN], shemA[NN], shemB[NN];
    __shared__ float shcdnA[NN * 3], shcdnB[NN * 3];

    if (t < HH) {
        shPA[t] = P[rA * HH + t];
        shPB[t] = P[rB * HH + t];
        shw256[t] = ew1l[256 * HH + t];
        shw257[t] = ew1l[257 * HH + t];
        shEb2[t] = eb2l[t];
        shCb1[t] = cb1l[t];
        shCw2[t] = cw2l[t];
    }
    if (t < NN * 3) {
        shx[t] = x[g0 * 3 + t];
        shx0g[t] = x0[g0 * 3 + t];
    }
    __syncthreads();
    if (t < 2 * NN) {  // wave0: node A geometry, wave1: node B (wave-uniform)
        const int j = t & 63;
        const bool isB = (t >= NN);
        const int ni = isB ? iB : iA;
        float dx = shx[ni * 3 + 0] - shx[j * 3 + 0];
        float dy = shx[ni * 3 + 1] - shx[j * 3 + 1];
        float dz = shx[ni * 3 + 2] - shx[j * 3 + 2];
        float rad = dx * dx + dy * dy + dz * dz;
        float inv = 1.0f / (sqrtf(rad + 1e-8f) + 1.0f);
        float ex = shx0g[ni * 3 + 0] - shx0g[j * 3 + 0];
        float ey = shx0g[ni * 3 + 1] - shx0g[j * 3 + 1];
        float ez = shx0g[ni * 3 + 2] - shx0g[j * 3 + 2];
        float ea = ex * ex + ey * ey + ez * ez;
        float* radp = isB ? shradB : shradA;
        float* eap  = isB ? sheaB : sheaA;
        float* emp  = isB ? shemB : shemA;
        float* cdnp = isB ? shcdnB : shcdnA;
        radp[j] = rad;
        eap[j] = ea;
        emp[j] = em[(isB ? rB : rA) * NN + j];
        cdnp[j * 3 + 0] = dx * inv;
        cdnp[j * 3 + 1] = dy * inv;
        cdnp[j * 3 + 2] = dz * inv;
    }
    __syncthreads();  // geometry done; shx0g overlay now dead

    // ---- build t1 rows for BOTH nodes (Q row loaded once, used twice) ----
    {
        const int j = t >> 2;  // 0..63
        const float radA = shradA[j], eaA = sheaA[j];
        const float radB = shradB[j], eaB = sheaB[j];
        const int xr = (j & 7) << 4;
#pragma unroll
        for (int p = 0; p < 4; ++p) {
            const int k0 = (t & 3) * 8 + p * 32;
            const float4 qa = *(const float4*)(Q + (size_t)(g0 + j) * HH + k0);
            const float4 qb = *(const float4*)(Q + (size_t)(g0 + j) * HH + k0 + 4);
            const float qv[8] = {qa.x, qa.y, qa.z, qa.w, qb.x, qb.y, qb.z, qb.w};
            uint32x4 sA, sB;
#pragma unroll
            for (int u2 = 0; u2 < 4; ++u2) {
                const int ka = k0 + 2 * u2, kb = ka + 1;
                const float w2a = shw256[ka], w3a = shw257[ka];
                const float w2b = shw256[kb], w3b = shw257[kb];
                float vA0 = silu_f(shPA[ka] + qv[2 * u2] + radA * w2a + eaA * w3a);
                float vA1 = silu_f(shPA[kb] + qv[2 * u2 + 1] + radA * w2b + eaA * w3b);
                float vB0 = silu_f(shPB[ka] + qv[2 * u2] + radB * w2a + eaB * w3a);
                float vB1 = silu_f(shPB[kb] + qv[2 * u2 + 1] + radB * w2b + eaB * w3b);
                sA[u2] = cvt_pk2(vA0, vA1);
                sB[u2] = cvt_pk2(vB0, vB1);
            }
            const int off = (k0 * 2) ^ xr;
            *(uint32x4*)(shAc + j * 256 + off) = sA;
            *(uint32x4*)(shAc + (j + 64) * 256 + off) = sB;  // (j+64)&7 == j&7
        }
    }
    __syncthreads();

    // ---- GEMM2: m = silu(t1 @ ew2 + eb2) * em  (col-sliced, B double-buffered) ----
    f32x4 acc[8][2];
#pragma unroll
    for (int rt = 0; rt < 8; ++rt) {
        acc[rt][0] = (f32x4){0.f, 0.f, 0.f, 0.f};
        acc[rt][1] = (f32x4){0.f, 0.f, 0.f, 0.f};
    }
    {
        const short* B2 = ew2T + (size_t)(c0 + l15) * HH + l4 * 8;
        bf16x8 bcur[2], bnxt[2];
        bcur[0] = *(const bf16x8*)(B2);
        bcur[1] = *(const bf16x8*)(B2 + 16 * HH);
#pragma unroll
        for (int kt = 0; kt < 4; ++kt) {
            if (kt < 3) {
                bnxt[0] = *(const bf16x8*)(B2 + (kt + 1) * 32);
                bnxt[1] = *(const bf16x8*)(B2 + 16 * HH + (kt + 1) * 32);
            }
            bf16x8 af[8];
#pragma unroll
            for (int rt = 0; rt < 8; ++rt) {
                const int row = rt * 16 + l15;
                af[rt] = *(const bf16x8*)(shAc + row * 256 + (((kt * 4 + l4) * 16) ^ ((row & 7) << 4)));
            }
#pragma unroll
            for (int rt = 0; rt < 8; ++rt) {
                acc[rt][0] = __builtin_amdgcn_mfma_f32_16x16x32_bf16(af[rt], bcur[0], acc[rt][0], 0, 0, 0);
                acc[rt][1] = __builtin_amdgcn_mfma_f32_16x16x32_bf16(af[rt], bcur[1], acc[rt][1], 0, 0, 0);
            }
            bcur[0] = bnxt[0];
            bcur[1] = bnxt[1];
        }
    }
    __syncthreads();  // GEMM2 A-reads done before m overwrites shAc

    // epilogue: m = silu(acc+eb2)*em -> shAc; agg in-wave for both nodes
#pragma unroll
    for (int ct2 = 0; ct2 < 2; ++ct2) {
        const int c = c0 + ct2 * 16 + l15;
        const float b = shEb2[c];
        float paggA = 0.0f, paggB = 0.0f;
#pragma unroll
        for (int rt = 0; rt < 8; ++rt) {
            const int rbase = rt * 16 + l4 * 4;
            float v[4];
#pragma unroll
            for (int reg = 0; reg < 4; ++reg) {
                const int row = rbase + reg;
                const float emv = (rt < 4) ? shemA[row] : shemB[row - 64];
                v[reg] = silu_f(acc[rt][ct2][reg] + b) * emv;
                if (rt < 4) paggA += v[reg]; else paggB += v[reg];
            }
            const unsigned wlo = cvt_pk2(v[0], v[1]);
            const unsigned whi = cvt_pk2(v[2], v[3]);
            const int cx = c * 2;
#pragma unroll
            for (int reg = 0; reg < 4; ++reg) {
                const int row = rbase + reg;
                const unsigned wv = (reg < 2) ? wlo : whi;
                const short sv = (reg & 1) ? (short)(wv >> 16) : (short)(wv & 0xffff);
                *(short*)(shAc + row * 256 + (cx ^ ((row & 7) << 4))) = sv;
            }
        }
        paggA += __shfl_xor(paggA, 16);
        paggA += __shfl_xor(paggA, 32);
        paggB += __shfl_xor(paggB, 16);
        paggB += __shfl_xor(paggB, 32);
        if (l4 == 0) {
            agg[rA * HH + c] = paggA;
            agg[rB * HH + c] = paggB;
        }
    }
    __syncthreads();  // m complete before GEMM3 A reads

    // ---- GEMM3: c1 = m @ cw1 ----
#pragma unroll
    for (int rt = 0; rt < 8; ++rt) {
        acc[rt][0] = (f32x4){0.f, 0.f, 0.f, 0.f};
        acc[rt][1] = (f32x4){0.f, 0.f, 0.f, 0.f};
    }
    {
        const short* B3 = cw1T + (size_t)(c0 + l15) * HH + l4 * 8;
        bf16x8 bcur[2], bnxt[2];
        bcur[0] = *(const bf16x8*)(B3);
        bcur[1] = *(const bf16x8*)(B3 + 16 * HH);
#pragma unroll
        for (int kt = 0; kt < 4; ++kt) {
            if (kt < 3) {
                bnxt[0] = *(const bf16x8*)(B3 + (kt + 1) * 32);
                bnxt[1] = *(const bf16x8*)(B3 + 16 * HH + (kt + 1) * 32);
            }
            bf16x8 af[8];
#pragma unroll
            for (int rt = 0; rt < 8; ++rt) {
                const int row = rt * 16 + l15;
                af[rt] = *(const bf16x8*)(shAc + row * 256 + (((kt * 4 + l4) * 16) ^ ((row & 7) << 4)));
            }
#pragma unroll
            for (int rt = 0; rt < 8; ++rt) {
                acc[rt][0] = __builtin_amdgcn_mfma_f32_16x16x32_bf16(af[rt], bcur[0], acc[rt][0], 0, 0, 0);
                acc[rt][1] = __builtin_amdgcn_mfma_f32_16x16x32_bf16(af[rt], bcur[1], acc[rt][1], 0, 0, 0);
            }
            bcur[0] = bnxt[0];
            bcur[1] = bnxt[1];
        }
    }

    // epilogue: phi partials, reduce over l15 within wave
    float pp[8][4];
    {
#pragma unroll
        for (int rt = 0; rt < 8; ++rt)
#pragma unroll
            for (int reg = 0; reg < 4; ++reg) pp[rt][reg] = 0.0f;
#pragma unroll
        for (int ct2 = 0; ct2 < 2; ++ct2) {
            const int c = c0 + ct2 * 16 + l15;
            const float cb = shCb1[c], cw = shCw2[c];
#pragma unroll
            for (int rt = 0; rt < 8; ++rt) {
#pragma unroll
                for (int reg = 0; reg < 4; ++reg) {
                    float v = silu_f(acc[rt][ct2][reg] + cb);
                    pp[rt][reg] = fmaf(v, cw, pp[rt][reg]);
                }
            }
        }
#pragma unroll
        for (int off = 8; off >= 1; off >>= 1) {
#pragma unroll
            for (int rt = 0; rt < 8; ++rt)
#pragma unroll
                for (int reg = 0; reg < 4; ++reg) pp[rt][reg] += __shfl_xor(pp[rt][reg], off);
        }
    }
    __syncthreads();  // ALL GEMM3 shAc reads done -> shphiP overlay safe
    if (l15 == 0) {
#pragma unroll
        for (int rt = 0; rt < 8; ++rt)
#pragma unroll
            for (int reg = 0; reg < 4; ++reg)
                shphiP[w * 128 + rt * 16 + l4 * 4 + reg] = pp[rt][reg];
    }
    __syncthreads();

    // x_out for both nodes (3 waves, one per coord; two sequential reductions)
    if (t < 192) {
        const int q = t >> 6, j = t & 63;
        float phiA = shphiP[0 * 128 + j] + shphiP[1 * 128 + j] + shphiP[2 * 128 + j] + shphiP[3 * 128 + j];
        float vA = shcdnA[j * 3 + q] * phiA * shemA[j];
        float phiB = shphiP[0 * 128 + 64 + j] + shphiP[1 * 128 + 64 + j] + shphiP[2 * 128 + 64 + j] + shphiP[3 * 128 + 64 + j];
        float vB = shcdnB[j * 3 + q] * phiB * shemB[j];
#pragma unroll
        for (int off = 32; off >= 1; off >>= 1) {
            vA += __shfl_xor(vA, off);
            vB += __shfl_xor(vB, off);
        }
        if (j == 0) {
            x_out[rA * 3 + q] = shx[iA * 3 + q] + vA;
            x_out[rB * 3 + q] = shx[iB * 3 + q] + vB;
        }
    }
}

// ---------------- fused: node update (in place) + NEXT layer's P,Q ----------------
// grid 256: 16 nodes/block. Wave w: cols [w*32, w*32+32).
__global__ __launch_bounds__(256) void nodepq_kernel(
    float* __restrict__ h, const float* __restrict__ agg, const float* __restrict__ nm,
    const short* __restrict__ nw1Tl, const float* __restrict__ nb1l,
    const short* __restrict__ nw2Tl, const float* __restrict__ nb2l,
    const short* __restrict__ ew1Tn, const float* __restrict__ eb1n,  // next layer
    float* __restrict__ P, float* __restrict__ Q, int do_pq) {
    const int g0n = blockIdx.x * 16;
    const int t = threadIdx.x;
    const int w = t >> 6, l = t & 63, l15 = l & 15, l4 = l >> 4;
    __shared__ __align__(16) char shN[16 * 512];  // [16 rows][256 bf16] = [h|agg], swizzled
    __shared__ __align__(16) char shT[16 * 256];  // [16 rows][128 bf16], swizzled
    char* shH = shN;  // reuse (dead after first GEMM) for new-h staging [16][128]

    {
        const int row = t >> 4, k0 = (t & 15) * 16;
        const float* src = (k0 < HH) ? (h + (size_t)(g0n + row) * HH + k0)
                                     : (agg + (size_t)(g0n + row) * HH + (k0 - HH));
        const float4 a = *(const float4*)src;
        const float4 b = *(const float4*)(src + 4);
        const float4 c = *(const float4*)(src + 8);
        const float4 d = *(const float4*)(src + 12);
        uint32x4 s0, s1;
        s0[0] = cvt_pk2(a.x, a.y); s0[1] = cvt_pk2(a.z, a.w);
        s0[2] = cvt_pk2(b.x, b.y); s0[3] = cvt_pk2(b.z, b.w);
        s1[0] = cvt_pk2(c.x, c.y); s1[1] = cvt_pk2(c.z, c.w);
        s1[2] = cvt_pk2(d.x, d.y); s1[3] = cvt_pk2(d.z, d.w);
        const int xr = (row & 7) << 4;
        *(uint32x4*)(shN + row * 512 + ((k0 * 2) ^ xr)) = s0;
        *(uint32x4*)(shN + row * 512 + ((k0 * 2 + 16) ^ xr)) = s1;
    }
    __syncthreads();

    const int c0 = w * 32;
    f32x4 acc[2];
    acc[0] = (f32x4){0.f, 0.f, 0.f, 0.f};
    acc[1] = (f32x4){0.f, 0.f, 0.f, 0.f};
#pragma unroll
    for (int kt = 0; kt < 8; ++kt) {
        const bf16x8 af = *(const bf16x8*)(shN + l15 * 512 + (((kt * 4 + l4) * 16) ^ ((l15 & 7) << 4)));
#pragma unroll
        for (int ct2 = 0; ct2 < 2; ++ct2) {
            const bf16x8 bf = *(const bf16x8*)(nw1Tl + (size_t)(c0 + ct2 * 16 + l15) * 256 + kt * 32 + l4 * 8);
            acc[ct2] = __builtin_amdgcn_mfma_f32_16x16x32_bf16(af, bf, acc[ct2], 0, 0, 0);
        }
    }
    __syncthreads();  // all shN reads done (shH overwrite below must not race)
#pragma unroll
    for (int ct2 = 0; ct2 < 2; ++ct2) {
        const int c = c0 + ct2 * 16 + l15;
        const float b = nb1l[c];
        float v[4];
#pragma unroll
        for (int reg = 0; reg < 4; ++reg) v[reg] = silu_f(acc[ct2][reg] + b);
        const unsigned wlo = cvt_pk2(v[0], v[1]);
        const unsigned whi = cvt_pk2(v[2], v[3]);
#pragma unroll
        for (int reg = 0; reg < 4; ++reg) {
            const int row = l4 * 4 + reg;
            const unsigned wv = (reg < 2) ? wlo : whi;
            const short sv = (reg & 1) ? (short)(wv >> 16) : (short)(wv & 0xffff);
            *(short*)(shT + row * 256 + ((c * 2) ^ ((row & 7) << 4))) = sv;
        }
    }
    __syncthreads();

    acc[0] = (f32x4){0.f, 0.f, 0.f, 0.f};
    acc[1] = (f32x4){0.f, 0.f, 0.f, 0.f};
#pragma unroll
    for (int kt = 0; kt < 4; ++kt) {
        const bf16x8 af = *(const bf16x8*)(shT + l15 * 256 + (((kt * 4 + l4) * 16) ^ ((l15 & 7) << 4)));
#pragma unroll
        for (int ct2 = 0; ct2 < 2; ++ct2) {
            const bf16x8 bf = *(const bf16x8*)(nw2Tl + (size_t)(c0 + ct2 * 16 + l15) * HH + kt * 32 + l4 * 8);
            acc[ct2] = __builtin_amdgcn_mfma_f32_16x16x32_bf16(af, bf, acc[ct2], 0, 0, 0);
        }
    }
    // h' = (h + mlp + b)*nm : write global, stage bf16 into shH for pq
    float hn[2][4];
#pragma unroll
    for (int ct2 = 0; ct2 < 2; ++ct2) {
        const int c = c0 + ct2 * 16 + l15;
        const float b = nb2l[c];
#pragma unroll
        for (int reg = 0; reg < 4; ++reg) {
            const int n = g0n + l4 * 4 + reg;
            const float hv = h[(size_t)n * HH + c];
            hn[ct2][reg] = (hv + acc[ct2][reg] + b) * nm[n];
            h[(size_t)n * HH + c] = hn[ct2][reg];
        }
    }
    if (!do_pq) return;

#pragma unroll
    for (int ct2 = 0; ct2 < 2; ++ct2) {
        const int c = c0 + ct2 * 16 + l15;
        const unsigned wlo = cvt_pk2(hn[ct2][0], hn[ct2][1]);
        const unsigned whi = cvt_pk2(hn[ct2][2], hn[ct2][3]);
#pragma unroll
        for (int reg = 0; reg < 4; ++reg) {
            const int row = l4 * 4 + reg;
            const unsigned wv = (reg < 2) ? wlo : whi;
            const short sv = (reg & 1) ? (short)(wv >> 16) : (short)(wv & 0xffff);
            *(short*)(shH + row * 256 + ((c * 2) ^ ((row & 7) << 4))) = sv;
        }
    }
    __syncthreads();

    // pq GEMM: 256 output cols; wave w covers c' = half*128 + [c0, c0+32)
    f32x4 pacc[2][2];
#pragma unroll
    for (int half = 0; half < 2; ++half) {
        pacc[half][0] = (f32x4){0.f, 0.f, 0.f, 0.f};
        pacc[half][1] = (f32x4){0.f, 0.f, 0.f, 0.f};
    }
#pragma unroll
    for (int kt = 0; kt < 4; ++kt) {
        const bf16x8 af = *(const bf16x8*)(shH + l15 * 256 + (((kt * 4 + l4) * 16) ^ ((l15 & 7) << 4)));
#pragma unroll
        for (int half = 0; half < 2; ++half) {
#pragma unroll
            for (int ct2 = 0; ct2 < 2; ++ct2) {
                const bf16x8 bf = *(const bf16x8*)(ew1Tn + (size_t)(half * 128 + c0 + ct2 * 16 + l15) * HH + kt * 32 + l4 * 8);
                pacc[half][ct2] = __builtin_amdgcn_mfma_f32_16x16x32_bf16(af, bf, pacc[half][ct2], 0, 0, 0);
            }
        }
    }
#pragma unroll
    for (int half = 0; half < 2; ++half) {
#pragma unroll
        for (int ct2 = 0; ct2 < 2; ++ct2) {
            const int cp = half * 128 + c0 + ct2 * 16 + l15;
            const int c = cp & 127;
            float* dst = (cp >= HH) ? Q : P;
            const float bias = (cp >= HH) ? 0.0f : eb1n[c];
#pragma unroll
            for (int reg = 0; reg < 4; ++reg) {
                const int n = g0n + l4 * 4 + reg;
                dst[(size_t)n * HH + c] = pacc[half][ct2][reg] + bias;
            }
        }
    }
}

// ---------------- output: per-graph mean of (h@out_w + out_b)*nm ----------------
__global__ void out_kernel(const float* __restrict__ h, const float* __restrict__ nm,
                           const float* __restrict__ ow, const float* __restrict__ ob,
                           float* __restrict__ out) {
    const int b = blockIdx.x;
    const int n = threadIdx.x;  // 64
    const int v = b * NN + n;
    float acc = 0.0f;
#pragma unroll 8
    for (int c = 0; c < HH; ++c) acc = fmaf(h[v * HH + c], ow[c], acc);
    acc = (acc + ob[0]) * nm[v];
#pragma unroll
    for (int off = 32; off >= 1; off >>= 1) acc += __shfl_xor(acc, off);
    if (n == 0) out[b] = acc * (1.0f / (float)NN);
}

extern "C" void kernel_launch(void* const* d_in, const int* in_sizes, int n_in,
                              void* d_out, int out_size, void* d_ws, size_t ws_size,
                              hipStream_t stream) {
    const float* xh    = (const float*)d_in[0];
    const float* nmask = (const float*)d_in[1];
    const float* emask = (const float*)d_in[2];
    const float* emb_w = (const float*)d_in[3];
    const float* emb_b = (const float*)d_in[4];
    const float* out_w = (const float*)d_in[5];
    const float* out_b = (const float*)d_in[6];
    const float* ew1   = (const float*)d_in[7];
    const float* eb1   = (const float*)d_in[8];
    const float* ew2   = (const float*)d_in[9];
    const float* eb2   = (const float*)d_in[10];
    const float* nw1   = (const float*)d_in[11];
    const float* nb1   = (const float*)d_in[12];
    const float* nw2   = (const float*)d_in[13];
    const float* nb2   = (const float*)d_in[14];
    const float* cw1   = (const float*)d_in[15];
    const float* cb1   = (const float*)d_in[16];
    const float* cw2   = (const float*)d_in[17];

    float* ws  = (float*)d_ws;
    float* xA  = ws;                    // [4096*3]
    float* xB  = xA + BNODES * 3;       // [4096*3]
    float* x0  = xB + BNODES * 3;       // [4096*3]
    float* h   = x0 + BNODES * 3;       // [4096*128]
    float* Pb  = h + BNODES * HH;       // [4096*128]
    float* Qb  = Pb + BNODES * HH;      // [4096*128]
    float* agg = Qb + BNODES * HH;      // [4096*128]
    short* ew2T = (short*)(agg + BNODES * HH);  // [4][128*128] bf16
    short* cw1T = ew2T + LL * HH * HH;          // [4][128*128] bf16
    short* ew1T = cw1T + LL * HH * HH;          // [4][256*128] bf16
    short* nw1T = ew1T + LL * 256 * HH;         // [4][128*256] bf16
    short* nw2T = nw1T + LL * 256 * HH;         // [4][128*128] bf16

    prep_kernel<<<BNODES, HH, 0, stream>>>(xh, nmask, emb_w, emb_b, xA, x0, h);
    wprep_kernel<<<5 * LL, 256, 0, stream>>>(ew1, ew2, cw1, nw1, nw2,
                                             ew1T, ew2T, cw1T, nw1T, nw2T);

    pq_kernel<<<512, 256, 0, stream>>>(h, ew1T, eb1, Pb, Qb);

    float* xc = xA;
    float* xn = xB;
    for (int l = 0; l < LL; ++l) {
        const float* ew1l = ew1 + (size_t)l * 258 * HH;
        edge_kernel<<<BNODES / 2, 256, 0, stream>>>(Pb, Qb, xc, x0, emask, ew1l,
                                                    ew2T + (size_t)l * HH * HH, eb2 + l * HH,
                                                    cw1T + (size_t)l * HH * HH, cb1 + l * HH,
                                                    cw2 + (size_t)l * HH, xn, agg);
        const int do_pq = (l + 1 < LL) ? 1 : 0;
        const int ln = do_pq ? (l + 1) : 0;
        nodepq_kernel<<<256, 256, 0, stream>>>(h, agg, nmask,
                                               nw1T + (size_t)l * 2 * HH * HH, nb1 + l * HH,
                                               nw2T + (size_t)l * HH * HH, nb2 + l * HH,
                                               ew1T + (size_t)ln * 256 * HH, eb1 + ln * HH,
                                               Pb, Qb, do_pq);
        float* tmp = xc; xc = xn; xn = tmp;
    }

    out_kernel<<<NB, NN, 0, stream>>>(h, nmask, out_w, out_b, (float*)d_out);
}

// Round 9
// 267.916 us; speedup vs baseline: 4.7459x; 1.0620x over previous
//
#include <hip/hip_runtime.h>
#include <math.h>

// EGNN: B=64 graphs x N=64 nodes, D=3, IN_NF=8, H=128, L=4 layers.
// R9: XCD-affinity blockIdx swizzle. All blocks reading graph g's P/Q/em
// panels decode to blockIdx % 8 == g % 8 -> same XCD -> panel fetched into
// that XCD's L2 once (was 8x HBM duplication, FETCH 14.3MB vs ~5MB useful).
// nodepq (P/Q writer) uses the same mapping so writer/reader XCDs match.

#define NB 64
#define NN 64
#define DD 3
#define INNF 8
#define HH 128
#define LL 4
#define BNODES (NB * NN)  // 4096

typedef __attribute__((ext_vector_type(8))) short bf16x8;
typedef __attribute__((ext_vector_type(4))) float f32x4;
typedef __attribute__((ext_vector_type(4))) unsigned uint32x4;

__device__ __forceinline__ float silu_f(float v) {
    float e = __expf(-v);
    return v * __builtin_amdgcn_rcpf(1.0f + e);
}

__device__ __forceinline__ short f2bf(float v) {
    unsigned u = __builtin_bit_cast(unsigned, v);
    u += 0x7fffu + ((u >> 16) & 1u);  // RNE (finite values only)
    return (short)(u >> 16);
}

// HW packed convert: lo -> bits[15:0], hi -> bits[31:16], RNE.
__device__ __forceinline__ unsigned cvt_pk2(float lo, float hi) {
    unsigned r;
    asm("v_cvt_pk_bf16_f32 %0, %1, %2" : "=v"(r) : "v"(lo), "v"(hi));
    return r;
}

// ---------------- prep: x, x0, h = (feat*nm)@emb_w + emb_b ----------------
__global__ void prep_kernel(const float* __restrict__ xh, const float* __restrict__ nm,
                            const float* __restrict__ emb_w, const float* __restrict__ emb_b,
                            float* __restrict__ x, float* __restrict__ x0, float* __restrict__ h) {
    const int v = blockIdx.x;
    const int t = threadIdx.x;  // 128
    const float m = nm[v];
    __shared__ float f[INNF];
    if (t < INNF) f[t] = xh[v * (DD + INNF) + DD + t] * m;
    if (t < DD) {
        float c = xh[v * (DD + INNF) + t] * m;
        x[v * DD + t] = c;
        x0[v * DD + t] = c;
    }
    __syncthreads();
    float acc = emb_b[t];
#pragma unroll
    for (int k = 0; k < INNF; ++k) acc = fmaf(f[k], emb_w[k * HH + t], acc);
    h[v * HH + t] = acc;
}

// ---------------- weight prep: bf16, K-contiguous per output column ----------------
__global__ void wprep_kernel(const float* __restrict__ ew1, const float* __restrict__ ew2,
                             const float* __restrict__ cw1, const float* __restrict__ nw1,
                             const float* __restrict__ nw2,
                             short* __restrict__ ew1T, short* __restrict__ ew2T,
                             short* __restrict__ cw1T, short* __restrict__ nw1T,
                             short* __restrict__ nw2T) {
    const int l = blockIdx.x / 5, which = blockIdx.x % 5;
    if (which == 0) {
        const float* src = ew1 + (size_t)l * 258 * HH;
        short* dst = ew1T + (size_t)l * 256 * HH;
        for (int idx = threadIdx.x; idx < 256 * HH; idx += blockDim.x) {
            const int cp = idx >> 7, k = idx & 127;
            dst[cp * HH + k] = f2bf(src[(k + ((cp >> 7) << 7)) * HH + (cp & 127)]);
        }
    } else if (which == 3) {
        const float* src = nw1 + (size_t)l * 2 * HH * HH;
        short* dst = nw1T + (size_t)l * 2 * HH * HH;
        for (int idx = threadIdx.x; idx < 2 * HH * HH; idx += blockDim.x) {
            const int c = idx >> 8, k = idx & 255;
            dst[c * 256 + k] = f2bf(src[k * HH + c]);
        }
    } else {
        const float* src = (which == 1 ? ew2 : which == 2 ? cw1 : nw2) + (size_t)l * HH * HH;
        short* dst = (which == 1 ? ew2T : which == 2 ? cw1T : nw2T) + (size_t)l * HH * HH;
        for (int idx = threadIdx.x; idx < HH * HH; idx += blockDim.x) {
            const int k = idx >> 7, c = idx & 127;
            dst[c * HH + k] = f2bf(src[idx]);
        }
    }
}

// ---------------- layer-0 pq: P = h@Wr + eb1, Q = h@Wc (bf16 MFMA) ----------------
// grid 512, XCD swizzle: g = bid&63, q = (bid>>6)&3, half = bid>>8.
__global__ __launch_bounds__(256) void pq_kernel(const float* __restrict__ h,
                                                 const short* __restrict__ ew1Tl,
                                                 const float* __restrict__ eb1l,
                                                 float* __restrict__ P, float* __restrict__ Q) {
    const int gph = blockIdx.x & 63;
    const int g0n = gph * NN + ((blockIdx.x >> 6) & 3) * 16;
    const int half = blockIdx.x >> 8;
    const int t = threadIdx.x;
    const int w = t >> 6, l = t & 63, l15 = l & 15, l4 = l >> 4;
    __shared__ __align__(16) char shN[16 * 256];

    {
        const int row = t >> 4, k0 = (t & 15) * 8;
        const float* hp = h + (size_t)(g0n + row) * HH + k0;
        const float4 a = *(const float4*)hp;
        const float4 b = *(const float4*)(hp + 4);
        uint32x4 s;
        s[0] = cvt_pk2(a.x, a.y);
        s[1] = cvt_pk2(a.z, a.w);
        s[2] = cvt_pk2(b.x, b.y);
        s[3] = cvt_pk2(b.z, b.w);
        *(uint32x4*)(shN + row * 256 + ((k0 * 2) ^ ((row & 7) << 4))) = s;
    }
    __syncthreads();

    const int c0 = half * 128 + w * 32;
    f32x4 acc[2];
    acc[0] = (f32x4){0.f, 0.f, 0.f, 0.f};
    acc[1] = (f32x4){0.f, 0.f, 0.f, 0.f};
#pragma unroll
    for (int kt = 0; kt < 4; ++kt) {
        const bf16x8 af = *(const bf16x8*)(shN + l15 * 256 + (((kt * 4 + l4) * 16) ^ ((l15 & 7) << 4)));
#pragma unroll
        for (int ct2 = 0; ct2 < 2; ++ct2) {
            const bf16x8 bf = *(const bf16x8*)(ew1Tl + (size_t)(c0 + ct2 * 16 + l15) * HH + kt * 32 + l4 * 8);
            acc[ct2] = __builtin_amdgcn_mfma_f32_16x16x32_bf16(af, bf, acc[ct2], 0, 0, 0);
        }
    }
#pragma unroll
    for (int ct2 = 0; ct2 < 2; ++ct2) {
        const int cp = c0 + ct2 * 16 + l15;
        const int c = cp & 127;
        float* dst = (cp >= HH) ? Q : P;
        const float bias = (cp >= HH) ? 0.0f : eb1l[c];
#pragma unroll
        for (int reg = 0; reg < 4; ++reg) {
            const int n = g0n + l4 * 4 + reg;
            dst[(size_t)n * HH + c] = acc[ct2][reg] + bias;
        }
    }
}

// ---------------- per-layer edge kernel: TWO row-nodes per block ----------------
// grid 2048, XCD swizzle: g = bid&63, ii = bid>>6 -> bid%8 == g%8 (same XCD per graph).
__global__ __launch_bounds__(256, 4) void edge_kernel(
    const float* __restrict__ P, const float* __restrict__ Q,
    const float* __restrict__ x, const float* __restrict__ x0,
    const float* __restrict__ em,
    const float* __restrict__ ew1l,   // [258][128] (rows 256,257 used)
    const short* __restrict__ ew2T,   // [128 cols][128 k] bf16
    const float* __restrict__ eb2l,
    const short* __restrict__ cw1T,   // [128 cols][128 k] bf16
    const float* __restrict__ cb1l,
    const float* __restrict__ cw2l,
    float* __restrict__ x_out, float* __restrict__ agg) {

    const int g  = blockIdx.x & 63;   // graph -> fixed XCD (bid % 8 == g % 8)
    const int ii = blockIdx.x >> 6;   // 0..31
    const int iA = ii, iB = ii + 32;
    const int g0 = g * NN;
    const int rA = g0 + iA, rB = g0 + iB;
    const int t = threadIdx.x;       // 256
    const int w = t >> 6;
    const int l = t & 63;
    const int l15 = l & 15, l4 = l >> 4;
    const int c0 = w * 32;

    __shared__ __align__(16) char shAc[128 * 256];  // rows 0-63: node A, 64-127: node B (32 KB)
    float* shphiP = (float*)(shAc);        // overlay: used only AFTER GEMM3 reads
    float* shx0g  = (float*)(shAc + 2048); // overlay: used only BEFORE build writes
    __shared__ float shPA[HH], shPB[HH], shw256[HH], shw257[HH];
    __shared__ float shEb2[HH], shCb1[HH], shCw2[HH];
    __shared__ float shx[NN * 3];
    __shared__ float shradA[NN], shradB[NN], sheaA[NN], sheaB[NN], shemA[NN], shemB[NN];
    __shared__ float shcdnA[NN * 3], shcdnB[NN * 3];

    if (t < HH) {
        shPA[t] = P[rA * HH + t];
        shPB[t] = P[rB * HH + t];
        shw256[t] = ew1l[256 * HH + t];
        shw257[t] = ew1l[257 * HH + t];
        shEb2[t] = eb2l[t];
        shCb1[t] = cb1l[t];
        shCw2[t] = cw2l[t];
    }
    if (t < NN * 3) {
        shx[t] = x[g0 * 3 + t];
        shx0g[t] = x0[g0 * 3 + t];
    }
    __syncthreads();
    if (t < 2 * NN) {  // wave0: node A geometry, wave1: node B (wave-uniform)
        const int j = t & 63;
        const bool isB = (t >= NN);
        const int ni = isB ? iB : iA;
        float dx = shx[ni * 3 + 0] - shx[j * 3 + 0];
        float dy = shx[ni * 3 + 1] - shx[j * 3 + 1];
        float dz = shx[ni * 3 + 2] - shx[j * 3 + 2];
        float rad = dx * dx + dy * dy + dz * dz;
        float inv = 1.0f / (sqrtf(rad + 1e-8f) + 1.0f);
        float ex = shx0g[ni * 3 + 0] - shx0g[j * 3 + 0];
        float ey = shx0g[ni * 3 + 1] - shx0g[j * 3 + 1];
        float ez = shx0g[ni * 3 + 2] - shx0g[j * 3 + 2];
        float ea = ex * ex + ey * ey + ez * ez;
        float* radp = isB ? shradB : shradA;
        float* eap  = isB ? sheaB : sheaA;
        float* emp  = isB ? shemB : shemA;
        float* cdnp = isB ? shcdnB : shcdnA;
        radp[j] = rad;
        eap[j] = ea;
        emp[j] = em[(isB ? rB : rA) * NN + j];
        cdnp[j * 3 + 0] = dx * inv;
        cdnp[j * 3 + 1] = dy * inv;
        cdnp[j * 3 + 2] = dz * inv;
    }
    __syncthreads();  // geometry done; shx0g overlay now dead

    // ---- build t1 rows for BOTH nodes (Q row loaded once, used twice) ----
    {
        const int j = t >> 2;  // 0..63
        const float radA = shradA[j], eaA = sheaA[j];
        const float radB = shradB[j], eaB = sheaB[j];
        const int xr = (j & 7) << 4;
#pragma unroll
        for (int p = 0; p < 4; ++p) {
            const int k0 = (t & 3) * 8 + p * 32;
            const float4 qa = *(const float4*)(Q + (size_t)(g0 + j) * HH + k0);
            const float4 qb = *(const float4*)(Q + (size_t)(g0 + j) * HH + k0 + 4);
            const float qv[8] = {qa.x, qa.y, qa.z, qa.w, qb.x, qb.y, qb.z, qb.w};
            uint32x4 sA, sB;
#pragma unroll
            for (int u2 = 0; u2 < 4; ++u2) {
                const int ka = k0 + 2 * u2, kb = ka + 1;
                const float w2a = shw256[ka], w3a = shw257[ka];
                const float w2b = shw256[kb], w3b = shw257[kb];
                float vA0 = silu_f(shPA[ka] + qv[2 * u2] + radA * w2a + eaA * w3a);
                float vA1 = silu_f(shPA[kb] + qv[2 * u2 + 1] + radA * w2b + eaA * w3b);
                float vB0 = silu_f(shPB[ka] + qv[2 * u2] + radB * w2a + eaB * w3a);
                float vB1 = silu_f(shPB[kb] + qv[2 * u2 + 1] + radB * w2b + eaB * w3b);
                sA[u2] = cvt_pk2(vA0, vA1);
                sB[u2] = cvt_pk2(vB0, vB1);
            }
            const int off = (k0 * 2) ^ xr;
            *(uint32x4*)(shAc + j * 256 + off) = sA;
            *(uint32x4*)(shAc + (j + 64) * 256 + off) = sB;  // (j+64)&7 == j&7
        }
    }
    __syncthreads();

    // ---- GEMM2: m = silu(t1 @ ew2 + eb2) * em  (col-sliced, B double-buffered) ----
    f32x4 acc[8][2];
#pragma unroll
    for (int rt = 0; rt < 8; ++rt) {
        acc[rt][0] = (f32x4){0.f, 0.f, 0.f, 0.f};
        acc[rt][1] = (f32x4){0.f, 0.f, 0.f, 0.f};
    }
    {
        const short* B2 = ew2T + (size_t)(c0 + l15) * HH + l4 * 8;
        bf16x8 bcur[2], bnxt[2];
        bcur[0] = *(const bf16x8*)(B2);
        bcur[1] = *(const bf16x8*)(B2 + 16 * HH);
#pragma unroll
        for (int kt = 0; kt < 4; ++kt) {
            if (kt < 3) {
                bnxt[0] = *(const bf16x8*)(B2 + (kt + 1) * 32);
                bnxt[1] = *(const bf16x8*)(B2 + 16 * HH + (kt + 1) * 32);
            }
            bf16x8 af[8];
#pragma unroll
            for (int rt = 0; rt < 8; ++rt) {
                const int row = rt * 16 + l15;
                af[rt] = *(const bf16x8*)(shAc + row * 256 + (((kt * 4 + l4) * 16) ^ ((row & 7) << 4)));
            }
#pragma unroll
            for (int rt = 0; rt < 8; ++rt) {
                acc[rt][0] = __builtin_amdgcn_mfma_f32_16x16x32_bf16(af[rt], bcur[0], acc[rt][0], 0, 0, 0);
                acc[rt][1] = __builtin_amdgcn_mfma_f32_16x16x32_bf16(af[rt], bcur[1], acc[rt][1], 0, 0, 0);
            }
            bcur[0] = bnxt[0];
            bcur[1] = bnxt[1];
        }
    }
    __syncthreads();  // GEMM2 A-reads done before m overwrites shAc

    // epilogue: m = silu(acc+eb2)*em -> shAc; agg in-wave for both nodes
#pragma unroll
    for (int ct2 = 0; ct2 < 2; ++ct2) {
        const int c = c0 + ct2 * 16 + l15;
        const float b = shEb2[c];
        float paggA = 0.0f, paggB = 0.0f;
#pragma unroll
        for (int rt = 0; rt < 8; ++rt) {
            const int rbase = rt * 16 + l4 * 4;
            float v[4];
#pragma unroll
            for (int reg = 0; reg < 4; ++reg) {
                const int row = rbase + reg;
                const float emv = (rt < 4) ? shemA[row] : shemB[row - 64];
                v[reg] = silu_f(acc[rt][ct2][reg] + b) * emv;
                if (rt < 4) paggA += v[reg]; else paggB += v[reg];
            }
            const unsigned wlo = cvt_pk2(v[0], v[1]);
            const unsigned whi = cvt_pk2(v[2], v[3]);
            const int cx = c * 2;
#pragma unroll
            for (int reg = 0; reg < 4; ++reg) {
                const int row = rbase + reg;
                const unsigned wv = (reg < 2) ? wlo : whi;
                const short sv = (reg & 1) ? (short)(wv >> 16) : (short)(wv & 0xffff);
                *(short*)(shAc + row * 256 + (cx ^ ((row & 7) << 4))) = sv;
            }
        }
        paggA += __shfl_xor(paggA, 16);
        paggA += __shfl_xor(paggA, 32);
        paggB += __shfl_xor(paggB, 16);
        paggB += __shfl_xor(paggB, 32);
        if (l4 == 0) {
            agg[rA * HH + c] = paggA;
            agg[rB * HH + c] = paggB;
        }
    }
    __syncthreads();  // m complete before GEMM3 A reads

    // ---- GEMM3: c1 = m @ cw1 ----
#pragma unroll
    for (int rt = 0; rt < 8; ++rt) {
        acc[rt][0] = (f32x4){0.f, 0.f, 0.f, 0.f};
        acc[rt][1] = (f32x4){0.f, 0.f, 0.f, 0.f};
    }
    {
        const short* B3 = cw1T + (size_t)(c0 + l15) * HH + l4 * 8;
        bf16x8 bcur[2], bnxt[2];
        bcur[0] = *(const bf16x8*)(B3);
        bcur[1] = *(const bf16x8*)(B3 + 16 * HH);
#pragma unroll
        for (int kt = 0; kt < 4; ++kt) {
            if (kt < 3) {
                bnxt[0] = *(const bf16x8*)(B3 + (kt + 1) * 32);
                bnxt[1] = *(const bf16x8*)(B3 + 16 * HH + (kt + 1) * 32);
            }
            bf16x8 af[8];
#pragma unroll
            for (int rt = 0; rt < 8; ++rt) {
                const int row = rt * 16 + l15;
                af[rt] = *(const bf16x8*)(shAc + row * 256 + (((kt * 4 + l4) * 16) ^ ((row & 7) << 4)));
            }
#pragma unroll
            for (int rt = 0; rt < 8; ++rt) {
                acc[rt][0] = __builtin_amdgcn_mfma_f32_16x16x32_bf16(af[rt], bcur[0], acc[rt][0], 0, 0, 0);
                acc[rt][1] = __builtin_amdgcn_mfma_f32_16x16x32_bf16(af[rt], bcur[1], acc[rt][1], 0, 0, 0);
            }
            bcur[0] = bnxt[0];
            bcur[1] = bnxt[1];
        }
    }

    // epilogue: phi partials, reduce over l15 within wave
    float pp[8][4];
    {
#pragma unroll
        for (int rt = 0; rt < 8; ++rt)
#pragma unroll
            for (int reg = 0; reg < 4; ++reg) pp[rt][reg] = 0.0f;
#pragma unroll
        for (int ct2 = 0; ct2 < 2; ++ct2) {
            const int c = c0 + ct2 * 16 + l15;
            const float cb = shCb1[c], cw = shCw2[c];
#pragma unroll
            for (int rt = 0; rt < 8; ++rt) {
#pragma unroll
                for (int reg = 0; reg < 4; ++reg) {
                    float v = silu_f(acc[rt][ct2][reg] + cb);
                    pp[rt][reg] = fmaf(v, cw, pp[rt][reg]);
                }
            }
        }
#pragma unroll
        for (int off = 8; off >= 1; off >>= 1) {
#pragma unroll
            for (int rt = 0; rt < 8; ++rt)
#pragma unroll
                for (int reg = 0; reg < 4; ++reg) pp[rt][reg] += __shfl_xor(pp[rt][reg], off);
        }
    }
    __syncthreads();  // ALL GEMM3 shAc reads done -> shphiP overlay safe
    if (l15 == 0) {
#pragma unroll
        for (int rt = 0; rt < 8; ++rt)
#pragma unroll
            for (int reg = 0; reg < 4; ++reg)
                shphiP[w * 128 + rt * 16 + l4 * 4 + reg] = pp[rt][reg];
    }
    __syncthreads();

    // x_out for both nodes (3 waves, one per coord; two sequential reductions)
    if (t < 192) {
        const int q = t >> 6, j = t & 63;
        float phiA = shphiP[0 * 128 + j] + shphiP[1 * 128 + j] + shphiP[2 * 128 + j] + shphiP[3 * 128 + j];
        float vA = shcdnA[j * 3 + q] * phiA * shemA[j];
        float phiB = shphiP[0 * 128 + 64 + j] + shphiP[1 * 128 + 64 + j] + shphiP[2 * 128 + 64 + j] + shphiP[3 * 128 + 64 + j];
        float vB = shcdnB[j * 3 + q] * phiB * shemB[j];
#pragma unroll
        for (int off = 32; off >= 1; off >>= 1) {
            vA += __shfl_xor(vA, off);
            vB += __shfl_xor(vB, off);
        }
        if (j == 0) {
            x_out[rA * 3 + q] = shx[iA * 3 + q] + vA;
            x_out[rB * 3 + q] = shx[iB * 3 + q] + vB;
        }
    }
}

// ---------------- fused: node update (in place) + NEXT layer's P,Q ----------------
// grid 256, XCD swizzle: g = bid&63, quarter = bid>>6 -> writer XCD == reader XCD.
__global__ __launch_bounds__(256) void nodepq_kernel(
    float* __restrict__ h, const float* __restrict__ agg, const float* __restrict__ nm,
    const short* __restrict__ nw1Tl, const float* __restrict__ nb1l,
    const short* __restrict__ nw2Tl, const float* __restrict__ nb2l,
    const short* __restrict__ ew1Tn, const float* __restrict__ eb1n,  // next layer
    float* __restrict__ P, float* __restrict__ Q, int do_pq) {
    const int g0n = (blockIdx.x & 63) * NN + (blockIdx.x >> 6) * 16;
    const int t = threadIdx.x;
    const int w = t >> 6, l = t & 63, l15 = l & 15, l4 = l >> 4;
    __shared__ __align__(16) char shN[16 * 512];  // [16 rows][256 bf16] = [h|agg], swizzled
    __shared__ __align__(16) char shT[16 * 256];  // [16 rows][128 bf16], swizzled
    char* shH = shN;  // reuse (dead after first GEMM) for new-h staging [16][128]

    {
        const int row = t >> 4, k0 = (t & 15) * 16;
        const float* src = (k0 < HH) ? (h + (size_t)(g0n + row) * HH + k0)
                                     : (agg + (size_t)(g0n + row) * HH + (k0 - HH));
        const float4 a = *(const float4*)src;
        const float4 b = *(const float4*)(src + 4);
        const float4 c = *(const float4*)(src + 8);
        const float4 d = *(const float4*)(src + 12);
        uint32x4 s0, s1;
        s0[0] = cvt_pk2(a.x, a.y); s0[1] = cvt_pk2(a.z, a.w);
        s0[2] = cvt_pk2(b.x, b.y); s0[3] = cvt_pk2(b.z, b.w);
        s1[0] = cvt_pk2(c.x, c.y); s1[1] = cvt_pk2(c.z, c.w);
        s1[2] = cvt_pk2(d.x, d.y); s1[3] = cvt_pk2(d.z, d.w);
        const int xr = (row & 7) << 4;
        *(uint32x4*)(shN + row * 512 + ((k0 * 2) ^ xr)) = s0;
        *(uint32x4*)(shN + row * 512 + ((k0 * 2 + 16) ^ xr)) = s1;
    }
    __syncthreads();

    const int c0 = w * 32;
    f32x4 acc[2];
    acc[0] = (f32x4){0.f, 0.f, 0.f, 0.f};
    acc[1] = (f32x4){0.f, 0.f, 0.f, 0.f};
#pragma unroll
    for (int kt = 0; kt < 8; ++kt) {
        const bf16x8 af = *(const bf16x8*)(shN + l15 * 512 + (((kt * 4 + l4) * 16) ^ ((l15 & 7) << 4)));
#pragma unroll
        for (int ct2 = 0; ct2 < 2; ++ct2) {
            const bf16x8 bf = *(const bf16x8*)(nw1Tl + (size_t)(c0 + ct2 * 16 + l15) * 256 + kt * 32 + l4 * 8);
            acc[ct2] = __builtin_amdgcn_mfma_f32_16x16x32_bf16(af, bf, acc[ct2], 0, 0, 0);
        }
    }
    __syncthreads();  // all shN reads done (shH overwrite below must not race)
#pragma unroll
    for (int ct2 = 0; ct2 < 2; ++ct2) {
        const int c = c0 + ct2 * 16 + l15;
        const float b = nb1l[c];
        float v[4];
#pragma unroll
        for (int reg = 0; reg < 4; ++reg) v[reg] = silu_f(acc[ct2][reg] + b);
        const unsigned wlo = cvt_pk2(v[0], v[1]);
        const unsigned whi = cvt_pk2(v[2], v[3]);
#pragma unroll
        for (int reg = 0; reg < 4; ++reg) {
            const int row = l4 * 4 + reg;
            const unsigned wv = (reg < 2) ? wlo : whi;
            const short sv = (reg & 1) ? (short)(wv >> 16) : (short)(wv & 0xffff);
            *(short*)(shT + row * 256 + ((c * 2) ^ ((row & 7) << 4))) = sv;
        }
    }
    __syncthreads();

    acc[0] = (f32x4){0.f, 0.f, 0.f, 0.f};
    acc[1] = (f32x4){0.f, 0.f, 0.f, 0.f};
#pragma unroll
    for (int kt = 0; kt < 4; ++kt) {
        const bf16x8 af = *(const bf16x8*)(shT + l15 * 256 + (((kt * 4 + l4) * 16) ^ ((l15 & 7) << 4)));
#pragma unroll
        for (int ct2 = 0; ct2 < 2; ++ct2) {
            const bf16x8 bf = *(const bf16x8*)(nw2Tl + (size_t)(c0 + ct2 * 16 + l15) * HH + kt * 32 + l4 * 8);
            acc[ct2] = __builtin_amdgcn_mfma_f32_16x16x32_bf16(af, bf, acc[ct2], 0, 0, 0);
        }
    }
    // h' = (h + mlp + b)*nm : write global, stage bf16 into shH for pq
    float hn[2][4];
#pragma unroll
    for (int ct2 = 0; ct2 < 2; ++ct2) {
        const int c = c0 + ct2 * 16 + l15;
        const float b = nb2l[c];
#pragma unroll
        for (int reg = 0; reg < 4; ++reg) {
            const int n = g0n + l4 * 4 + reg;
            const float hv = h[(size_t)n * HH + c];
            hn[ct2][reg] = (hv + acc[ct2][reg] + b) * nm[n];
            h[(size_t)n * HH + c] = hn[ct2][reg];
        }
    }
    if (!do_pq) return;

#pragma unroll
    for (int ct2 = 0; ct2 < 2; ++ct2) {
        const int c = c0 + ct2 * 16 + l15;
        const unsigned wlo = cvt_pk2(hn[ct2][0], hn[ct2][1]);
        const unsigned whi = cvt_pk2(hn[ct2][2], hn[ct2][3]);
#pragma unroll
        for (int reg = 0; reg < 4; ++reg) {
            const int row = l4 * 4 + reg;
            const unsigned wv = (reg < 2) ? wlo : whi;
            const short sv = (reg & 1) ? (short)(wv >> 16) : (short)(wv & 0xffff);
            *(short*)(shH + row * 256 + ((c * 2) ^ ((row & 7) << 4))) = sv;
        }
    }
    __syncthreads();

    // pq GEMM: 256 output cols; wave w covers c' = half*128 + [c0, c0+32)
    f32x4 pacc[2][2];
#pragma unroll
    for (int half = 0; half < 2; ++half) {
        pacc[half][0] = (f32x4){0.f, 0.f, 0.f, 0.f};
        pacc[half][1] = (f32x4){0.f, 0.f, 0.f, 0.f};
    }
#pragma unroll
    for (int kt = 0; kt < 4; ++kt) {
        const bf16x8 af = *(const bf16x8*)(shH + l15 * 256 + (((kt * 4 + l4) * 16) ^ ((l15 & 7) << 4)));
#pragma unroll
        for (int half = 0; half < 2; ++half) {
#pragma unroll
            for (int ct2 = 0; ct2 < 2; ++ct2) {
                const bf16x8 bf = *(const bf16x8*)(ew1Tn + (size_t)(half * 128 + c0 + ct2 * 16 + l15) * HH + kt * 32 + l4 * 8);
                pacc[half][ct2] = __builtin_amdgcn_mfma_f32_16x16x32_bf16(af, bf, pacc[half][ct2], 0, 0, 0);
            }
        }
    }
#pragma unroll
    for (int half = 0; half < 2; ++half) {
#pragma unroll
        for (int ct2 = 0; ct2 < 2; ++ct2) {
            const int cp = half * 128 + c0 + ct2 * 16 + l15;
            const int c = cp & 127;
            float* dst = (cp >= HH) ? Q : P;
            const float bias = (cp >= HH) ? 0.0f : eb1n[c];
#pragma unroll
            for (int reg = 0; reg < 4; ++reg) {
                const int n = g0n + l4 * 4 + reg;
                dst[(size_t)n * HH + c] = pacc[half][ct2][reg] + bias;
            }
        }
    }
}

// ---------------- output: per-graph mean of (h@out_w + out_b)*nm ----------------
__global__ void out_kernel(const float* __restrict__ h, const float* __restrict__ nm,
                           const float* __restrict__ ow, const float* __restrict__ ob,
                           float* __restrict__ out) {
    const int b = blockIdx.x;
    const int n = threadIdx.x;  // 64
    const int v = b * NN + n;
    float acc = 0.0f;
#pragma unroll 8
    for (int c = 0; c < HH; ++c) acc = fmaf(h[v * HH + c], ow[c], acc);
    acc = (acc + ob[0]) * nm[v];
#pragma unroll
    for (int off = 32; off >= 1; off >>= 1) acc += __shfl_xor(acc, off);
    if (n == 0) out[b] = acc * (1.0f / (float)NN);
}

extern "C" void kernel_launch(void* const* d_in, const int* in_sizes, int n_in,
                              void* d_out, int out_size, void* d_ws, size_t ws_size,
                              hipStream_t stream) {
    const float* xh    = (const float*)d_in[0];
    const float* nmask = (const float*)d_in[1];
    const float* emask = (const float*)d_in[2];
    const float* emb_w = (const float*)d_in[3];
    const float* emb_b = (const float*)d_in[4];
    const float* out_w = (const float*)d_in[5];
    const float* out_b = (const float*)d_in[6];
    const float* ew1   = (const float*)d_in[7];
    const float* eb1   = (const float*)d_in[8];
    const float* ew2   = (const float*)d_in[9];
    const float* eb2   = (const float*)d_in[10];
    const float* nw1   = (const float*)d_in[11];
    const float* nb1   = (const float*)d_in[12];
    const float* nw2   = (const float*)d_in[13];
    const float* nb2   = (const float*)d_in[14];
    const float* cw1   = (const float*)d_in[15];
    const float* cb1   = (const float*)d_in[16];
    const float* cw2   = (const float*)d_in[17];

    float* ws  = (float*)d_ws;
    float* xA  = ws;                    // [4096*3]
    float* xB  = xA + BNODES * 3;       // [4096*3]
    float* x0  = xB + BNODES * 3;       // [4096*3]
    float* h   = x0 + BNODES * 3;       // [4096*128]
    float* Pb  = h + BNODES * HH;       // [4096*128]
    float* Qb  = Pb + BNODES * HH;      // [4096*128]
    float* agg = Qb + BNODES * HH;      // [4096*128]
    short* ew2T = (short*)(agg + BNODES * HH);  // [4][128*128] bf16
    short* cw1T = ew2T + LL * HH * HH;          // [4][128*128] bf16
    short* ew1T = cw1T + LL * HH * HH;          // [4][256*128] bf16
    short* nw1T = ew1T + LL * 256 * HH;         // [4][128*256] bf16
    short* nw2T = nw1T + LL * 256 * HH;         // [4][128*128] bf16

    prep_kernel<<<BNODES, HH, 0, stream>>>(xh, nmask, emb_w, emb_b, xA, x0, h);
    wprep_kernel<<<5 * LL, 256, 0, stream>>>(ew1, ew2, cw1, nw1, nw2,
                                             ew1T, ew2T, cw1T, nw1T, nw2T);

    pq_kernel<<<512, 256, 0, stream>>>(h, ew1T, eb1, Pb, Qb);

    float* xc = xA;
    float* xn = xB;
    for (int l = 0; l < LL; ++l) {
        const float* ew1l = ew1 + (size_t)l * 258 * HH;
        edge_kernel<<<BNODES / 2, 256, 0, stream>>>(Pb, Qb, xc, x0, emask, ew1l,
                                                    ew2T + (size_t)l * HH * HH, eb2 + l * HH,
                                                    cw1T + (size_t)l * HH * HH, cb1 + l * HH,
                                                    cw2 + (size_t)l * HH, xn, agg);
        const int do_pq = (l + 1 < LL) ? 1 : 0;
        const int ln = do_pq ? (l + 1) : 0;
        nodepq_kernel<<<256, 256, 0, stream>>>(h, agg, nmask,
                                               nw1T + (size_t)l * 2 * HH * HH, nb1 + l * HH,
                                               nw2T + (size_t)l * HH * HH, nb2 + l * HH,
                                               ew1T + (size_t)ln * 256 * HH, eb1 + ln * HH,
                                               Pb, Qb, do_pq);
        float* tmp = xc; xc = xn; xn = tmp;
    }

    out_kernel<<<NB, NN, 0, stream>>>(h, nmask, out_w, out_b, (float*)d_out);
}